// Round 1
// baseline (892.617 us; speedup 1.0000x reference)
//
#include <hip/hip_runtime.h>
#include <stdint.h>

// Problem constants
constexpr int NHEADS = 8;
constexpr int SEQL   = 512;
constexpr int DM     = 256;
constexpr int NTOKENS = 8192;                 // B*S = 16*512
constexpr size_t NBUFE = (size_t)NTOKENS * DM; // 2,097,152 floats = 8MB

// ---------------- wave helpers ----------------
__device__ __forceinline__ float wred_sum(float v) {
#pragma unroll
  for (int d = 32; d >= 1; d >>= 1) v += __shfl_xor(v, d, 64);
  return v;
}
__device__ __forceinline__ float wred_max(float v) {
#pragma unroll
  for (int d = 32; d >= 1; d >>= 1) v = fmaxf(v, __shfl_xor(v, d, 64));
  return v;
}
__device__ __forceinline__ unsigned bf16rne(float x) {
  unsigned b = __float_as_uint(x);
  return (b + 0x7FFFu + ((b >> 16) & 1u)) >> 16;
}

// ---------------- GEMM: C[N,256] = A[N,256] @ W[256,256] + bias ----------------
// 64x64 tile, BK=32, k-major LDS tiles (pad 68), each thread 4x4.
__global__ __launch_bounds__(256, 4) void gemm_bias(
    const float* __restrict__ A, const float* __restrict__ W,
    const float* __restrict__ bias, float* __restrict__ C) {
  __shared__ float As[32][68];
  __shared__ float Ws[32][68];
  const int t = threadIdx.x;
  const int tx = t & 15, ty = t >> 4;
  const int row0 = blockIdx.x << 6, col0 = blockIdx.y << 6;
  float acc[4][4];
#pragma unroll
  for (int i = 0; i < 4; ++i)
#pragma unroll
    for (int j = 0; j < 4; ++j) acc[i][j] = 0.f;

  for (int k0 = 0; k0 < 256; k0 += 32) {
#pragma unroll
    for (int hh = 0; hh < 2; ++hh) {  // stage A tile: 64 rows x 32 k (transpose to k-major)
      int idx = (hh << 8) + t;
      int r = idx >> 3, ks = (idx & 7) << 2;
      float4 v = *(const float4*)&A[(size_t)(row0 + r) * DM + k0 + ks];
      As[ks + 0][r] = v.x; As[ks + 1][r] = v.y;
      As[ks + 2][r] = v.z; As[ks + 3][r] = v.w;
    }
#pragma unroll
    for (int hh = 0; hh < 2; ++hh) {  // stage W tile: 32 k x 64 cols
      int idx = (hh << 8) + t;
      int kk = idx >> 4, cs = (idx & 15) << 2;
      float4 v = *(const float4*)&W[(size_t)(k0 + kk) * DM + col0 + cs];
      *(float4*)&Ws[kk][cs] = v;
    }
    __syncthreads();
#pragma unroll
    for (int kk = 0; kk < 32; ++kk) {
      float4 a4 = *(const float4*)&As[kk][ty << 2];
      float4 w4 = *(const float4*)&Ws[kk][tx << 2];
      float aa[4] = {a4.x, a4.y, a4.z, a4.w};
      float ww[4] = {w4.x, w4.y, w4.z, w4.w};
#pragma unroll
      for (int i = 0; i < 4; ++i)
#pragma unroll
        for (int j = 0; j < 4; ++j) acc[i][j] = fmaf(aa[i], ww[j], acc[i][j]);
    }
    __syncthreads();
  }
  float4 b4 = *(const float4*)&bias[col0 + (tx << 2)];
#pragma unroll
  for (int i = 0; i < 4; ++i) {
    float4 o;
    o.x = acc[i][0] + b4.x; o.y = acc[i][1] + b4.y;
    o.z = acc[i][2] + b4.z; o.w = acc[i][3] + b4.w;
    *(float4*)&C[(size_t)(row0 + (ty << 2) + i) * DM + col0 + (tx << 2)] = o;
  }
}

// ---------------- fused attention (one WG per (b,h,half-of-rows)) ----------------
// Implements: scores = qk^T/sqrt(32); masked softmax (j<=i or j<=i-1); cumsum;
// dist = sqrt(clip((tot-cum)*|i-j|,0)); total = clip(exp(-softplus(gam)*dist),1e-5,1e5);
// p = softmax_UNMASKED(scores*total); optional p[i==0]=0; O = p @ V.
// LDS: K fp32 [512][32] chunk-XOR-swizzled (64KB) + V bf16-packed [512][16]u32 (32KB)
//      + per-wave p transpose buffers 8*[512][2] f32 (32KB) = 128KB dynamic.
__global__ __launch_bounds__(512, 2) void attn_fused(
    const float* __restrict__ Q, const float* __restrict__ Kg,
    const float* __restrict__ Vg, const float* __restrict__ gam,
    float* __restrict__ O, int qsb, int qss, int peek, int zero_pad) {
  extern __shared__ float smem[];
  float* Kl = smem;                              // 512*32 floats
  unsigned* Vl = (unsigned*)(smem + SEQL * 32);  // 512*16 u32
  float* pball = smem + SEQL * 32 + SEQL * 16;   // 8 waves * 1024 floats
  const int tid = threadIdx.x;
  const int lane = tid & 63, wave = tid >> 6;
  const int b = blockIdx.x >> 3, h = blockIdx.x & 7;
  const int half = blockIdx.y;
  float* pbuf = pball + (wave << 10);

  const float* Kbase = Kg + ((size_t)b * SEQL) * DM + h * 32;
  const float* Vbase = Vg + ((size_t)b * SEQL) * DM + h * 32;
#pragma unroll
  for (int it = 0; it < 8; ++it) {  // stage K (swizzled fp32)
    int idx = (it << 9) + tid;
    int j = idx >> 3, c = idx & 7;
    float4 v = *(const float4*)&Kbase[(size_t)j * DM + (c << 2)];
    *(float4*)&Kl[(j << 5) + ((c ^ (j & 7)) << 2)] = v;
  }
#pragma unroll
  for (int it = 0; it < 8; ++it) {  // stage V (bf16 packed, linear)
    int idx = (it << 9) + tid;
    int j = idx >> 3, c = idx & 7;
    float4 v = *(const float4*)&Vbase[(size_t)j * DM + (c << 2)];
    uint2 pk;
    pk.x = bf16rne(v.x) | (bf16rne(v.y) << 16);
    pk.y = bf16rne(v.z) | (bf16rne(v.w) << 16);
    *(uint2*)&Vl[(j << 4) + (c << 1)] = pk;
  }
  __syncthreads();

  const float gh = -log1pf(__expf(gam[h]));  // -softplus(gamma_h)
  const int cswz = lane & 7;                 // == j&7 for j = lane + 64u
  float jF[8];
#pragma unroll
  for (int u = 0; u < 8; ++u) jF[u] = (float)(lane + (u << 6));
  const float* qrow = Q + (size_t)b * qsb + h * 32;
  const int kpv = lane & 31;
  const int jh = lane >> 5;
  const bool hi16 = (kpv & 1) != 0;

  for (int grp = 0; grp < 4; ++grp) {
    const int i0 = (half << 8) + (wave << 5) + (grp << 3);  // 8 rows per group
    float s[8][8];
#pragma unroll
    for (int r = 0; r < 8; ++r)
#pragma unroll
      for (int u = 0; u < 8; ++u) s[r][u] = 0.f;

    // ---- phase A: scores for 8 rows x all 512 j (lane owns j = lane+64u)
#pragma unroll
    for (int c = 0; c < 8; ++c) {
      float4 q4[8];
#pragma unroll
      for (int r = 0; r < 8; ++r)
        q4[r] = *(const float4*)&qrow[(size_t)(i0 + r) * qss + (c << 2)];
      const int cc = (c ^ cswz) << 2;
#pragma unroll
      for (int u = 0; u < 8; ++u) {
        float4 k4 = *(const float4*)&Kl[((lane + (u << 6)) << 5) + cc];
#pragma unroll
        for (int r = 0; r < 8; ++r) {
          s[r][u] = fmaf(q4[r].x, k4.x, s[r][u]);
          s[r][u] = fmaf(q4[r].y, k4.y, s[r][u]);
          s[r][u] = fmaf(q4[r].z, k4.z, s[r][u]);
          s[r][u] = fmaf(q4[r].w, k4.w, s[r][u]);
        }
      }
    }
#pragma unroll
    for (int r = 0; r < 8; ++r)
#pragma unroll
      for (int u = 0; u < 8; ++u) s[r][u] *= 0.17677669529663687f;  // 1/sqrt(32)

    // ---- phase B: per-row middle (masked softmax -> cumsum -> decay -> unmasked softmax)
#pragma unroll
    for (int r = 0; r < 8; ++r) {
      const int i = i0 + r;
      const float iF = (float)i;
      const float lim = peek ? iF : (iF - 1.0f);
      float m1 = -1e30f;
#pragma unroll
      for (int u = 0; u < 8; ++u)
        m1 = fmaxf(m1, (jF[u] <= lim) ? s[r][u] : -1e30f);
      m1 = wred_max(m1);
      float e[8];
      float S1 = 0.f;
#pragma unroll
      for (int u = 0; u < 8; ++u) {
        float ex = __expf(s[r][u] - m1);
        ex = (jF[u] <= lim) ? ex : 0.f;  // inf/garbage discarded by select
        e[u] = ex;
        S1 += ex;
      }
      S1 = wred_sum(S1);
      const float inv1 = (S1 > 0.f) ? (1.f / S1) : 0.f;  // S1==0 only for block3 row 0
      float off = 0.f;
      float m2 = -1e30f;
#pragma unroll
      for (int u = 0; u < 8; ++u) {
        float v = e[u];
#pragma unroll
        for (int dd = 1; dd <= 32; dd <<= 1) {  // inclusive wave scan
          float tt = __shfl_up(v, dd, 64);
          v += (lane >= dd) ? tt : 0.f;
        }
        float cum = off + v;
        off += __shfl(v, 63, 64);
        float right = fmaxf((S1 - cum) * inv1, 0.f);         // disttot - distcum (normalized)
        float dist = sqrtf(right * fabsf(iF - jF[u]));
        float tot = __expf(gh * dist);
        tot = fminf(fmaxf(tot, 1e-5f), 1e5f);
        float s2 = s[r][u] * tot;
        s[r][u] = s2;
        m2 = fmaxf(m2, s2);
      }
      m2 = wred_max(m2);  // UNMASKED softmax over all 512
      float S2 = 0.f;
#pragma unroll
      for (int u = 0; u < 8; ++u) {
        float e2 = __expf(s[r][u] - m2);
        s[r][u] = e2;
        S2 += e2;
      }
      S2 = wred_sum(S2);
      float invs2 = 1.f / S2;
      if (zero_pad && i == 0) invs2 = 0.f;  // scores[:,:,0,:] = 0
#pragma unroll
      for (int u = 0; u < 8; ++u) s[r][u] *= invs2;
    }

    // ---- phase C: PV, 2 rows at a time via per-wave LDS p-transpose
#pragma unroll
    for (int r0 = 0; r0 < 8; r0 += 2) {
#pragma unroll
      for (int u = 0; u < 8; ++u) {
        float2 pp;
        pp.x = s[r0][u];
        pp.y = s[r0 + 1][u];
        *(float2*)&pbuf[(lane + (u << 6)) << 1] = pp;
      }
      asm volatile("s_waitcnt lgkmcnt(0)" ::: "memory");  // drain p writes (same wave)
      float a0 = 0.f, a1 = 0.f, a2 = 0.f, a3 = 0.f;
      const int jbase = jh << 8;
      for (int m = 0; m < 256; m += 2) {
        {
          int j = jbase + m;
          float2 p2 = *(const float2*)&pbuf[j << 1];
          unsigned vu = Vl[(j << 4) + (kpv >> 1)];
          float vv = __uint_as_float(hi16 ? (vu & 0xFFFF0000u) : (vu << 16));
          a0 = fmaf(p2.x, vv, a0);
          a1 = fmaf(p2.y, vv, a1);
        }
        {
          int j = jbase + m + 1;
          float2 p2 = *(const float2*)&pbuf[j << 1];
          unsigned vu = Vl[(j << 4) + (kpv >> 1)];
          float vv = __uint_as_float(hi16 ? (vu & 0xFFFF0000u) : (vu << 16));
          a2 = fmaf(p2.x, vv, a2);
          a3 = fmaf(p2.y, vv, a3);
        }
      }
      a0 += a2; a1 += a3;
      a0 += __shfl_xor(a0, 32, 64);  // combine j-halves
      a1 += __shfl_xor(a1, 32, 64);
      const int ro = i0 + r0 + jh;               // lower lanes store row r0, upper r0+1
      float val = (jh == 0) ? a0 : a1;
      O[((size_t)b * SEQL + ro) * DM + h * 32 + kpv] = val;
    }
  }
}

// ---------------- add + LayerNorm (one wave per row) ----------------
__global__ __launch_bounds__(256, 4) void add_ln(
    const float* __restrict__ x, const float* __restrict__ res, int res_stride,
    const float* __restrict__ g, const float* __restrict__ bb,
    float* __restrict__ out) {
  const int row = (blockIdx.x << 2) + (threadIdx.x >> 6);
  const int lane = threadIdx.x & 63;
  const size_t base = (size_t)row * DM + (lane << 2);
  float4 xv = *(const float4*)&x[base];
  float4 rv = *(const float4*)&res[(size_t)row * res_stride + (lane << 2)];
  float4 v;
  v.x = xv.x + rv.x; v.y = xv.y + rv.y; v.z = xv.z + rv.z; v.w = xv.w + rv.w;
  float s = v.x + v.y + v.z + v.w;
  s = wred_sum(s);
  const float mean = s * (1.f / 256.f);
  float4 d;
  d.x = v.x - mean; d.y = v.y - mean; d.z = v.z - mean; d.w = v.w - mean;
  float q = d.x * d.x + d.y * d.y + d.z * d.z + d.w * d.w;
  q = wred_sum(q);
  const float rstd = rsqrtf(q * (1.f / 256.f) + 1e-5f);
  float4 gv = *(const float4*)&g[lane << 2];
  float4 bv = *(const float4*)&bb[lane << 2];
  float4 o;
  o.x = fmaf(gv.x * d.x, rstd, bv.x);
  o.y = fmaf(gv.y * d.y, rstd, bv.y);
  o.z = fmaf(gv.z * d.z, rstd, bv.z);
  o.w = fmaf(gv.w * d.w, rstd, bv.w);
  *(float4*)&out[base] = o;
}

// ---------------- tiny precompute: q3 = know@b3_qw + b3_qb; key3[h,d] = sigmoid(know_h@lk_w + lk_b)
__global__ __launch_bounds__(256) void small_pre(
    const float* __restrict__ know, const float* __restrict__ qw,
    const float* __restrict__ qb, const float* __restrict__ lkw,
    const float* __restrict__ lkb, float* __restrict__ q3,
    float* __restrict__ key3) {
  const int d = threadIdx.x;
  float acc = qb[d];
  for (int kk = 0; kk < 256; ++kk) acc = fmaf(know[kk], qw[kk * 256 + d], acc);
  q3[d] = acc;
#pragma unroll
  for (int hh = 0; hh < 8; ++hh) {
    float a = lkb[d];
#pragma unroll
    for (int kk = 0; kk < 32; ++kk)
      a = fmaf(know[hh * 32 + kk], lkw[kk * 256 + d], a);
    key3[hh * 256 + d] = 1.f / (1.f + __expf(-a));
  }
}

// ---------------- final pooling: beta/alpha over heads, sigmoid value, weighted sum
__global__ __launch_bounds__(256, 4) void final_combine(
    const float* __restrict__ qe, const float* __restrict__ Hf,
    const float* __restrict__ key3, const float* __restrict__ lvw,
    const float* __restrict__ lvb, float* __restrict__ out) {
  __shared__ float hl[256];
  __shared__ float red[4][8];
  const int n = blockIdx.x, d = threadIdx.x;
  const int lane = d & 63, wv = d >> 6;
  hl[d] = Hf[(size_t)n * DM + d];
  const float qd = qe[(size_t)n * DM + d];
  float part[8];
#pragma unroll
  for (int hh = 0; hh < 8; ++hh) part[hh] = key3[hh * 256 + d] * qd;
#pragma unroll
  for (int hh = 0; hh < 8; ++hh) part[hh] = wred_sum(part[hh]);
  if (lane == 0) {
#pragma unroll
    for (int hh = 0; hh < 8; ++hh) red[wv][hh] = part[hh];
  }
  __syncthreads();
  float beta[8];
#pragma unroll
  for (int hh = 0; hh < 8; ++hh)
    beta[hh] = red[0][hh] + red[1][hh] + red[2][hh] + red[3][hh];
  float mb = beta[0];
#pragma unroll
  for (int hh = 1; hh < 8; ++hh) mb = fmaxf(mb, beta[hh]);
  float al[8];
  float se = 0.f;
#pragma unroll
  for (int hh = 0; hh < 8; ++hh) {
    al[hh] = __expf(beta[hh] - mb);
    se += al[hh];
  }
  const float inva = 1.f / se;
  float acc[8];
#pragma unroll
  for (int hh = 0; hh < 8; ++hh) acc[hh] = 0.f;
#pragma unroll
  for (int kk = 0; kk < 32; ++kk) {
    float w = lvw[kk * 256 + d];
#pragma unroll
    for (int hh = 0; hh < 8; ++hh) acc[hh] = fmaf(hl[hh * 32 + kk], w, acc[hh]);
  }
  const float bd = lvb[d];
  float o = 0.f;
#pragma unroll
  for (int hh = 0; hh < 8; ++hh) {
    float v = 1.f / (1.f + __expf(-(acc[hh] + bd)));
    o = fmaf(al[hh] * inva, v, o);
  }
  out[(size_t)n * DM + d] = o;
}

// ---------------- host launch ----------------
extern "C" void kernel_launch(void* const* d_in, const int* in_sizes, int n_in,
                              void* d_out, int out_size, void* d_ws, size_t ws_size,
                              hipStream_t stream) {
  (void)in_sizes; (void)n_in; (void)out_size; (void)ws_size;
  const float* q_emb  = (const float*)d_in[0];
  const float* qa_emb = (const float*)d_in[1];
  const float* b1_qw = (const float*)d_in[2];   const float* b1_qb = (const float*)d_in[3];
  const float* b1_vw = (const float*)d_in[4];   const float* b1_vb = (const float*)d_in[5];
  const float* b1_ow = (const float*)d_in[6];   const float* b1_ob = (const float*)d_in[7];
  const float* b1_gam = (const float*)d_in[8];
  const float* b1_lng = (const float*)d_in[9];  const float* b1_lnb = (const float*)d_in[10];
  const float* b2_qw = (const float*)d_in[11];  const float* b2_qb = (const float*)d_in[12];
  const float* b2_vw = (const float*)d_in[13];  const float* b2_vb = (const float*)d_in[14];
  const float* b2_ow = (const float*)d_in[15];  const float* b2_ob = (const float*)d_in[16];
  const float* b2_gam = (const float*)d_in[17];
  const float* b2_lng = (const float*)d_in[18]; const float* b2_lnb = (const float*)d_in[19];
  const float* b3_qw = (const float*)d_in[20];  const float* b3_qb = (const float*)d_in[21];
  const float* b3_kw = (const float*)d_in[22];  const float* b3_kb = (const float*)d_in[23];
  const float* b3_vw = (const float*)d_in[24];  const float* b3_vb = (const float*)d_in[25];
  const float* b3_ow = (const float*)d_in[26];  const float* b3_ob = (const float*)d_in[27];
  const float* b3_gam = (const float*)d_in[28];
  const float* b3_lng = (const float*)d_in[29]; const float* b3_lnb = (const float*)d_in[30];
  const float* know = (const float*)d_in[31];
  const float* lk_w = (const float*)d_in[32];   const float* lk_b = (const float*)d_in[33];
  const float* lv_w = (const float*)d_in[34];   const float* lv_b = (const float*)d_in[35];

  float* ws = (float*)d_ws;   // needs ~59MB of workspace
  float* Qb = ws;
  float* Vb = ws + NBUFE;
  float* Ab = ws + 2 * NBUFE;
  float* Ob = ws + 3 * NBUFE;
  float* HQ = ws + 4 * NBUFE;
  float* HA = ws + 5 * NBUFE;
  float* Hf = ws + 6 * NBUFE;
  float* q3 = ws + 7 * NBUFE;
  float* key3 = q3 + 256;

  (void)hipFuncSetAttribute(reinterpret_cast<const void*>(attn_fused),
                            hipFuncAttributeMaxDynamicSharedMemorySize, 131072);

  const dim3 gg(128, 4), gb(256);
  const dim3 ga(128, 2);
  const int SMB = 131072;

  // block 1 (input q_emb; k == q)
  gemm_bias<<<gg, gb, 0, stream>>>(q_emb, b1_qw, b1_qb, Qb);
  gemm_bias<<<gg, gb, 0, stream>>>(q_emb, b1_vw, b1_vb, Vb);
  attn_fused<<<ga, 512, SMB, stream>>>(Qb, Qb, Vb, b1_gam, Ab, SEQL * DM, DM, 1, 0);
  gemm_bias<<<gg, gb, 0, stream>>>(Ab, b1_ow, b1_ob, Ob);
  add_ln<<<2048, 256, 0, stream>>>(Ob, q_emb, DM, b1_lng, b1_lnb, HQ);

  // block 2 (input qa_emb; k == q)
  gemm_bias<<<gg, gb, 0, stream>>>(qa_emb, b2_qw, b2_qb, Qb);
  gemm_bias<<<gg, gb, 0, stream>>>(qa_emb, b2_vw, b2_vb, Vb);
  attn_fused<<<ga, 512, SMB, stream>>>(Qb, Qb, Vb, b2_gam, Ab, SEQL * DM, DM, 1, 0);
  gemm_bias<<<gg, gb, 0, stream>>>(Ab, b2_ow, b2_ob, Ob);
  add_ln<<<2048, 256, 0, stream>>>(Ob, qa_emb, DM, b2_lng, b2_lnb, HA);

  // block 3 (q = know@qw+qb broadcast; k from HQ, v from HA; strict mask; zero_pad)
  small_pre<<<1, 256, 0, stream>>>(know, b3_qw, b3_qb, lk_w, lk_b, q3, key3);
  gemm_bias<<<gg, gb, 0, stream>>>(HQ, b3_kw, b3_kb, Qb);
  gemm_bias<<<gg, gb, 0, stream>>>(HA, b3_vw, b3_vb, Vb);
  attn_fused<<<ga, 512, SMB, stream>>>(q3, Qb, Vb, b3_gam, Ab, 0, 0, 0, 1);
  gemm_bias<<<gg, gb, 0, stream>>>(Ab, b3_ow, b3_ob, Ob);
  add_ln<<<2048, 256, 0, stream>>>(Ob, know, 0, b3_lng, b3_lnb, Hf);

  // final pooling
  final_combine<<<8192, 256, 0, stream>>>(q_emb, Hf, key3, lv_w, lv_b, (float*)d_out);
}

// Round 2
// 641.899 us; speedup vs baseline: 1.3906x; 1.3906x over previous
//
#include <hip/hip_runtime.h>
#include <stdint.h>

// Problem constants
constexpr int SEQL   = 512;
constexpr int DM     = 256;
constexpr int NTOKENS = 8192;                 // B*S = 16*512
constexpr size_t NBUFE = (size_t)NTOKENS * DM; // 2,097,152 floats = 8MB

typedef __attribute__((ext_vector_type(4))) float f32x4;
typedef __attribute__((ext_vector_type(8))) short short8;

// ---------------- wave helpers ----------------
__device__ __forceinline__ float wred_sum(float v) {
#pragma unroll
  for (int d = 32; d >= 1; d >>= 1) v += __shfl_xor(v, d, 64);
  return v;
}
__device__ __forceinline__ unsigned bf16rne(float x) {
  unsigned b = __float_as_uint(x);
  return (b + 0x7FFFu + ((b >> 16) & 1u)) >> 16;
}

// ---------------- GEMM: C[N,256] = A[N,256] @ W[256,256] + bias ----------------
__global__ __launch_bounds__(256, 4) void gemm_bias(
    const float* __restrict__ A, const float* __restrict__ W,
    const float* __restrict__ bias, float* __restrict__ C) {
  __shared__ float As[32][68];
  __shared__ float Ws[32][68];
  const int t = threadIdx.x;
  const int tx = t & 15, ty = t >> 4;
  const int row0 = blockIdx.x << 6, col0 = blockIdx.y << 6;
  float acc[4][4];
#pragma unroll
  for (int i = 0; i < 4; ++i)
#pragma unroll
    for (int j = 0; j < 4; ++j) acc[i][j] = 0.f;

  for (int k0 = 0; k0 < 256; k0 += 32) {
#pragma unroll
    for (int hh = 0; hh < 2; ++hh) {
      int idx = (hh << 8) + t;
      int r = idx >> 3, ks = (idx & 7) << 2;
      float4 v = *(const float4*)&A[(size_t)(row0 + r) * DM + k0 + ks];
      As[ks + 0][r] = v.x; As[ks + 1][r] = v.y;
      As[ks + 2][r] = v.z; As[ks + 3][r] = v.w;
    }
#pragma unroll
    for (int hh = 0; hh < 2; ++hh) {
      int idx = (hh << 8) + t;
      int kk = idx >> 4, cs = (idx & 15) << 2;
      float4 v = *(const float4*)&W[(size_t)(k0 + kk) * DM + col0 + cs];
      *(float4*)&Ws[kk][cs] = v;
    }
    __syncthreads();
#pragma unroll
    for (int kk = 0; kk < 32; ++kk) {
      float4 a4 = *(const float4*)&As[kk][ty << 2];
      float4 w4 = *(const float4*)&Ws[kk][tx << 2];
      float aa[4] = {a4.x, a4.y, a4.z, a4.w};
      float ww[4] = {w4.x, w4.y, w4.z, w4.w};
#pragma unroll
      for (int i = 0; i < 4; ++i)
#pragma unroll
        for (int j = 0; j < 4; ++j) acc[i][j] = fmaf(aa[i], ww[j], acc[i][j]);
    }
    __syncthreads();
  }
  float4 b4 = *(const float4*)&bias[col0 + (tx << 2)];
#pragma unroll
  for (int i = 0; i < 4; ++i) {
    float4 o;
    o.x = acc[i][0] + b4.x; o.y = acc[i][1] + b4.y;
    o.z = acc[i][2] + b4.z; o.w = acc[i][3] + b4.w;
    *(float4*)&C[(size_t)(row0 + (ty << 2) + i) * DM + col0 + (tx << 2)] = o;
  }
}

// ---------------- fused attention, MFMA version ----------------
// One WG per (b,h,half). 8 waves; each wave handles 16 query rows per block,
// 2 blocks (32 rows) => 256 rows per WG.
// Swapped QK^T: s_tile = mfma(A=K_tile, B=Q^T) so lane owns ONE query row
// (i = i0 + (lane&15)) and, via K row-permutation rho(j), a CONTIGUOUS j-block
// [128g, 128g+128) spread over 32 tiles x 4 regs (j = 128g + 32q + t).
// Middle phase (masked softmax -> cumsum -> decay -> unmasked softmax) is then
// per-lane serial + 3-shuffle cross-group scan.
// PV: contraction order pi(j) chosen so the A-fragment of step st is the
// static register slice s[(st&3)*8+r][st>>2]; V pre-scattered at staging into
// per-(step,dtile) fragment order -> single linear ds_read_b128 per B-frag.
__global__ __launch_bounds__(512, 2) void attn_fused(
    const float* __restrict__ Q, const float* __restrict__ Kg,
    const float* __restrict__ Vg, const float* __restrict__ gam,
    float* __restrict__ O, int qsb, int qss, int peek, int zero_pad) {
  extern __shared__ char smem[];
  char* KlB = smem;              // 32KB: K bf16, row rho(j), 64B rows
  char* VfB = smem + 32768;      // 32KB: V frags [16 st][2 dt][64 lane][16B]
  const int tid = threadIdx.x;
  const int lane = tid & 63, wave = tid >> 6;
  const int b = blockIdx.x >> 3, h = blockIdx.x & 7;
  const int half = blockIdx.y;
  const int g = lane >> 4, c = lane & 15;

  const float* Kbase = Kg + ((size_t)b * SEQL) * DM + h * 32;
  const float* Vbase = Vg + ((size_t)b * SEQL) * DM + h * 32;
#pragma unroll
  for (int it = 0; it < 8; ++it) {
    int idx = (it << 9) + tid;
    int j = idx >> 3, c4 = idx & 7;
    float4 kv = *(const float4*)&Kbase[(size_t)j * DM + (c4 << 2)];
    int rho = ((j & 31) << 4) + ((j >> 7) << 2) + ((j >> 5) & 3);
    uint2 kp;
    kp.x = bf16rne(kv.x) | (bf16rne(kv.y) << 16);
    kp.y = bf16rne(kv.z) | (bf16rne(kv.w) << 16);
    *(uint2*)(KlB + rho * 64 + c4 * 8) = kp;
    float4 vv = *(const float4*)&Vbase[(size_t)j * DM + (c4 << 2)];
    int pi = (((j >> 5) & 3) << 7) + (((j >> 3) & 3) << 5) + ((j >> 7) << 3) + (j & 7);
    int st = pi >> 5;
    int slot = pi & 7;
    int lanebase = ((pi & 31) >> 3) << 4;
    int d0 = c4 << 2;
    int dt = d0 >> 4;
    char* cb = VfB + (((st << 1) + dt) << 10) + (lanebase << 4) + (slot << 1);
    *(unsigned short*)(cb + (((d0 & 15) + 0) << 4)) = (unsigned short)bf16rne(vv.x);
    *(unsigned short*)(cb + (((d0 & 15) + 1) << 4)) = (unsigned short)bf16rne(vv.y);
    *(unsigned short*)(cb + (((d0 & 15) + 2) << 4)) = (unsigned short)bf16rne(vv.z);
    *(unsigned short*)(cb + (((d0 & 15) + 3) << 4)) = (unsigned short)bf16rne(vv.w);
  }
  __syncthreads();

  const float gh = -log1pf(__expf(gam[h]));  // -softplus(gamma_h)
  const char* kfb = KlB + c * 64 + (g << 4); // K A-frag base (per lane)
  const char* vfb = VfB + (lane << 4);       // V B-frag base (per lane)

  for (int blk = 0; blk < 2; ++blk) {
    const int i0 = (half << 8) + (blk << 7) + (wave << 4);
    const int i_row = i0 + c;

    // ---- Q B-fragment (col = lane&15 = i, k = g*8 + r), scaled by 1/sqrt(32)
    const float* qr = Q + (size_t)b * qsb + (size_t)i_row * qss + h * 32 + (g << 3);
    float4 qa = *(const float4*)qr;
    float4 qb2 = *(const float4*)(qr + 4);
    const float SC = 0.17677669529663687f;
    short8 qf;
    qf[0] = (short)bf16rne(qa.x * SC); qf[1] = (short)bf16rne(qa.y * SC);
    qf[2] = (short)bf16rne(qa.z * SC); qf[3] = (short)bf16rne(qa.w * SC);
    qf[4] = (short)bf16rne(qb2.x * SC); qf[5] = (short)bf16rne(qb2.y * SC);
    qf[6] = (short)bf16rne(qb2.z * SC); qf[7] = (short)bf16rne(qb2.w * SC);

    // ---- QK^T (swapped): s[t][q] = score(i_row, j = 128g + 32q + t)
    f32x4 s[32];
#pragma unroll
    for (int t = 0; t < 32; ++t) {
      short8 ka = *(const short8*)(kfb + (t << 10));
      s[t] = __builtin_amdgcn_mfma_f32_16x16x32_bf16(
          ka, qf, (f32x4){0.f, 0.f, 0.f, 0.f}, 0, 0, 0);
    }

    // ---- middle phase, per lane = one query row
    const int jb = g << 7;
    const int ilim = i_row - 1 + peek;               // mask: j <= ilim
    const int tl0 = ilim - jb, tl1 = tl0 - 32, tl2 = tl0 - 64, tl3 = tl0 - 96;

    float m1 = -3e38f;
#pragma unroll
    for (int t = 0; t < 32; ++t) {
      m1 = fmaxf(m1, (t <= tl0) ? s[t].x : -3e38f);
      m1 = fmaxf(m1, (t <= tl1) ? s[t].y : -3e38f);
      m1 = fmaxf(m1, (t <= tl2) ? s[t].z : -3e38f);
      m1 = fmaxf(m1, (t <= tl3) ? s[t].w : -3e38f);
    }
    m1 = fmaxf(m1, __shfl_xor(m1, 16, 64));
    m1 = fmaxf(m1, __shfl_xor(m1, 32, 64));

    float T0 = 0.f, T1 = 0.f, T2 = 0.f, T3 = 0.f;
#pragma unroll
    for (int t = 0; t < 32; ++t) {
      T0 += (t <= tl0) ? __expf(s[t].x - m1) : 0.f;
      T1 += (t <= tl1) ? __expf(s[t].y - m1) : 0.f;
      T2 += (t <= tl2) ? __expf(s[t].z - m1) : 0.f;
      T3 += (t <= tl3) ? __expf(s[t].w - m1) : 0.f;
    }
    float L = T0 + T1 + T2 + T3;
    float v = L;
    float u1 = __shfl_up(v, 16, 64); v += (g >= 1) ? u1 : 0.f;
    float u2 = __shfl_up(v, 32, 64); v += (g >= 2) ? u2 : 0.f;
    float S1 = __shfl(v, c + 48, 64);
    float X = v - L;                                  // exclusive prefix (this g)
    float inv1 = (S1 > 0.f) ? (1.f / S1) : 0.f;

    float r0 = X, r1 = X + T0, r2 = r1 + T1, r3 = r2 + T2;
    const float fi = (float)i_row;
    const float dj0 = fi - (float)jb, dj1 = dj0 - 32.f, dj2 = dj0 - 64.f, dj3 = dj0 - 96.f;
    float m2 = -3e38f;
#pragma unroll
    for (int t = 0; t < 32; ++t) {
      const float ft = (float)t;
      {
        float e = (t <= tl0) ? __expf(s[t].x - m1) : 0.f; r0 += e;
        float right = fmaxf((S1 - r0) * inv1, 0.f);
        float dist = sqrtf(right * fabsf(dj0 - ft));
        float tot = __expf(gh * dist);
        tot = fminf(fmaxf(tot, 1e-5f), 1e5f);
        float s2 = s[t].x * tot; s[t].x = s2; m2 = fmaxf(m2, s2);
      }
      {
        float e = (t <= tl1) ? __expf(s[t].y - m1) : 0.f; r1 += e;
        float right = fmaxf((S1 - r1) * inv1, 0.f);
        float dist = sqrtf(right * fabsf(dj1 - ft));
        float tot = __expf(gh * dist);
        tot = fminf(fmaxf(tot, 1e-5f), 1e5f);
        float s2 = s[t].y * tot; s[t].y = s2; m2 = fmaxf(m2, s2);
      }
      {
        float e = (t <= tl2) ? __expf(s[t].z - m1) : 0.f; r2 += e;
        float right = fmaxf((S1 - r2) * inv1, 0.f);
        float dist = sqrtf(right * fabsf(dj2 - ft));
        float tot = __expf(gh * dist);
        tot = fminf(fmaxf(tot, 1e-5f), 1e5f);
        float s2 = s[t].z * tot; s[t].z = s2; m2 = fmaxf(m2, s2);
      }
      {
        float e = (t <= tl3) ? __expf(s[t].w - m1) : 0.f; r3 += e;
        float right = fmaxf((S1 - r3) * inv1, 0.f);
        float dist = sqrtf(right * fabsf(dj3 - ft));
        float tot = __expf(gh * dist);
        tot = fminf(fmaxf(tot, 1e-5f), 1e5f);
        float s2 = s[t].w * tot; s[t].w = s2; m2 = fmaxf(m2, s2);
      }
    }
    m2 = fmaxf(m2, __shfl_xor(m2, 16, 64));
    m2 = fmaxf(m2, __shfl_xor(m2, 32, 64));

    float Sa = 0.f, Sb = 0.f, Sc = 0.f, Sd = 0.f;
#pragma unroll
    for (int t = 0; t < 32; ++t) {
      float ex = __expf(s[t].x - m2); s[t].x = ex; Sa += ex;
      float ey = __expf(s[t].y - m2); s[t].y = ey; Sb += ey;
      float ez = __expf(s[t].z - m2); s[t].z = ez; Sc += ez;
      float ew = __expf(s[t].w - m2); s[t].w = ew; Sd += ew;
    }
    float S2 = Sa + Sb + Sc + Sd;
    S2 += __shfl_xor(S2, 16, 64);
    S2 += __shfl_xor(S2, 32, 64);
    float inv2 = 1.f / S2;
    if (zero_pad && i_row == 0) inv2 = 0.f;           // scores[:,:,0,:] = 0

    // ---- PV: A-frag (p) straight from registers, B-frag (V) linear b128
    f32x4 acc0 = {0.f, 0.f, 0.f, 0.f}, acc1 = {0.f, 0.f, 0.f, 0.f};
#pragma unroll
    for (int st = 0; st < 16; ++st) {
      const int q = st >> 2, tb = (st & 3) << 3;
      short8 af;
#pragma unroll
      for (int r = 0; r < 8; ++r)
        af[r] = (short)bf16rne(s[tb + r][q] * inv2);
      short8 vb0 = *(const short8*)(vfb + ((st << 11) + 0));
      short8 vb1 = *(const short8*)(vfb + ((st << 11) + 1024));
      acc0 = __builtin_amdgcn_mfma_f32_16x16x32_bf16(af, vb0, acc0, 0, 0, 0);
      acc1 = __builtin_amdgcn_mfma_f32_16x16x32_bf16(af, vb1, acc1, 0, 0, 0);
    }

    // ---- write O: rows i0 + 4g + reg, cols h*32 + dt*16 + c
    float* orow = O + ((size_t)b * SEQL + i0 + (g << 2)) * DM + h * 32 + c;
#pragma unroll
    for (int reg = 0; reg < 4; ++reg) {
      orow[(size_t)reg * DM] = acc0[reg];
      orow[(size_t)reg * DM + 16] = acc1[reg];
    }
  }
}

// ---------------- add + LayerNorm (one wave per row) ----------------
__global__ __launch_bounds__(256, 4) void add_ln(
    const float* __restrict__ x, const float* __restrict__ res, int res_stride,
    const float* __restrict__ g, const float* __restrict__ bb,
    float* __restrict__ out) {
  const int row = (blockIdx.x << 2) + (threadIdx.x >> 6);
  const int lane = threadIdx.x & 63;
  const size_t base = (size_t)row * DM + (lane << 2);
  float4 xv = *(const float4*)&x[base];
  float4 rv = *(const float4*)&res[(size_t)row * res_stride + (lane << 2)];
  float4 v;
  v.x = xv.x + rv.x; v.y = xv.y + rv.y; v.z = xv.z + rv.z; v.w = xv.w + rv.w;
  float s = v.x + v.y + v.z + v.w;
  s = wred_sum(s);
  const float mean = s * (1.f / 256.f);
  float4 d;
  d.x = v.x - mean; d.y = v.y - mean; d.z = v.z - mean; d.w = v.w - mean;
  float q = d.x * d.x + d.y * d.y + d.z * d.z + d.w * d.w;
  q = wred_sum(q);
  const float rstd = rsqrtf(q * (1.f / 256.f) + 1e-5f);
  float4 gv = *(const float4*)&g[lane << 2];
  float4 bv = *(const float4*)&bb[lane << 2];
  float4 o;
  o.x = fmaf(gv.x * d.x, rstd, bv.x);
  o.y = fmaf(gv.y * d.y, rstd, bv.y);
  o.z = fmaf(gv.z * d.z, rstd, bv.z);
  o.w = fmaf(gv.w * d.w, rstd, bv.w);
  *(float4*)&out[base] = o;
}

// ---------------- tiny precompute ----------------
__global__ __launch_bounds__(256) void small_pre(
    const float* __restrict__ know, const float* __restrict__ qw,
    const float* __restrict__ qb, const float* __restrict__ lkw,
    const float* __restrict__ lkb, float* __restrict__ q3,
    float* __restrict__ key3) {
  const int d = threadIdx.x;
  float acc = qb[d];
  for (int kk = 0; kk < 256; ++kk) acc = fmaf(know[kk], qw[kk * 256 + d], acc);
  q3[d] = acc;
#pragma unroll
  for (int hh = 0; hh < 8; ++hh) {
    float a = lkb[d];
#pragma unroll
    for (int kk = 0; kk < 32; ++kk)
      a = fmaf(know[hh * 32 + kk], lkw[kk * 256 + d], a);
    key3[hh * 256 + d] = 1.f / (1.f + __expf(-a));
  }
}

// ---------------- final pooling ----------------
__global__ __launch_bounds__(256, 4) void final_combine(
    const float* __restrict__ qe, const float* __restrict__ Hf,
    const float* __restrict__ key3, const float* __restrict__ lvw,
    const float* __restrict__ lvb, float* __restrict__ out) {
  __shared__ float hl[256];
  __shared__ float red[4][8];
  const int n = blockIdx.x, d = threadIdx.x;
  const int lane = d & 63, wv = d >> 6;
  hl[d] = Hf[(size_t)n * DM + d];
  const float qd = qe[(size_t)n * DM + d];
  float part[8];
#pragma unroll
  for (int hh = 0; hh < 8; ++hh) part[hh] = key3[hh * 256 + d] * qd;
#pragma unroll
  for (int hh = 0; hh < 8; ++hh) part[hh] = wred_sum(part[hh]);
  if (lane == 0) {
#pragma unroll
    for (int hh = 0; hh < 8; ++hh) red[wv][hh] = part[hh];
  }
  __syncthreads();
  float beta[8];
#pragma unroll
  for (int hh = 0; hh < 8; ++hh)
    beta[hh] = red[0][hh] + red[1][hh] + red[2][hh] + red[3][hh];
  float mb = beta[0];
#pragma unroll
  for (int hh = 1; hh < 8; ++hh) mb = fmaxf(mb, beta[hh]);
  float al[8];
  float se = 0.f;
#pragma unroll
  for (int hh = 0; hh < 8; ++hh) {
    al[hh] = __expf(beta[hh] - mb);
    se += al[hh];
  }
  const float inva = 1.f / se;
  float acc[8];
#pragma unroll
  for (int hh = 0; hh < 8; ++hh) acc[hh] = 0.f;
#pragma unroll
  for (int kk = 0; kk < 32; ++kk) {
    float w = lvw[kk * 256 + d];
#pragma unroll
    for (int hh = 0; hh < 8; ++hh) acc[hh] = fmaf(hl[hh * 32 + kk], w, acc[hh]);
  }
  const float bd = lvb[d];
  float o = 0.f;
#pragma unroll
  for (int hh = 0; hh < 8; ++hh) {
    float vv = 1.f / (1.f + __expf(-(acc[hh] + bd)));
    o = fmaf(al[hh] * inva, vv, o);
  }
  out[(size_t)n * DM + d] = o;
}

// ---------------- host launch ----------------
extern "C" void kernel_launch(void* const* d_in, const int* in_sizes, int n_in,
                              void* d_out, int out_size, void* d_ws, size_t ws_size,
                              hipStream_t stream) {
  (void)in_sizes; (void)n_in; (void)out_size; (void)ws_size;
  const float* q_emb  = (const float*)d_in[0];
  const float* qa_emb = (const float*)d_in[1];
  const float* b1_qw = (const float*)d_in[2];   const float* b1_qb = (const float*)d_in[3];
  const float* b1_vw = (const float*)d_in[4];   const float* b1_vb = (const float*)d_in[5];
  const float* b1_ow = (const float*)d_in[6];   const float* b1_ob = (const float*)d_in[7];
  const float* b1_gam = (const float*)d_in[8];
  const float* b1_lng = (const float*)d_in[9];  const float* b1_lnb = (const float*)d_in[10];
  const float* b2_qw = (const float*)d_in[11];  const float* b2_qb = (const float*)d_in[12];
  const float* b2_vw = (const float*)d_in[13];  const float* b2_vb = (const float*)d_in[14];
  const float* b2_ow = (const float*)d_in[15];  const float* b2_ob = (const float*)d_in[16];
  const float* b2_gam = (const float*)d_in[17];
  const float* b2_lng = (const float*)d_in[18]; const float* b2_lnb = (const float*)d_in[19];
  const float* b3_qw = (const float*)d_in[20];  const float* b3_qb = (const float*)d_in[21];
  const float* b3_kw = (const float*)d_in[22];  const float* b3_kb = (const float*)d_in[23];
  const float* b3_vw = (const float*)d_in[24];  const float* b3_vb = (const float*)d_in[25];
  const float* b3_ow = (const float*)d_in[26];  const float* b3_ob = (const float*)d_in[27];
  const float* b3_gam = (const float*)d_in[28];
  const float* b3_lng = (const float*)d_in[29]; const float* b3_lnb = (const float*)d_in[30];
  const float* know = (const float*)d_in[31];
  const float* lk_w = (const float*)d_in[32];   const float* lk_b = (const float*)d_in[33];
  const float* lv_w = (const float*)d_in[34];   const float* lv_b = (const float*)d_in[35];

  float* ws = (float*)d_ws;
  float* Qb = ws;
  float* Vb = ws + NBUFE;
  float* Ab = ws + 2 * NBUFE;
  float* Ob = ws + 3 * NBUFE;
  float* HQ = ws + 4 * NBUFE;
  float* HA = ws + 5 * NBUFE;
  float* Hf = ws + 6 * NBUFE;
  float* q3 = ws + 7 * NBUFE;
  float* key3 = q3 + 256;

  (void)hipFuncSetAttribute(reinterpret_cast<const void*>(attn_fused),
                            hipFuncAttributeMaxDynamicSharedMemorySize, 65536);

  const dim3 gg(128, 4), gb(256);
  const dim3 ga(128, 2);
  const int SMB = 65536;

  // block 1 (input q_emb; k == q)
  gemm_bias<<<gg, gb, 0, stream>>>(q_emb, b1_qw, b1_qb, Qb);
  gemm_bias<<<gg, gb, 0, stream>>>(q_emb, b1_vw, b1_vb, Vb);
  attn_fused<<<ga, 512, SMB, stream>>>(Qb, Qb, Vb, b1_gam, Ab, SEQL * DM, DM, 1, 0);
  gemm_bias<<<gg, gb, 0, stream>>>(Ab, b1_ow, b1_ob, Ob);
  add_ln<<<2048, 256, 0, stream>>>(Ob, q_emb, DM, b1_lng, b1_lnb, HQ);

  // block 2 (input qa_emb; k == q)
  gemm_bias<<<gg, gb, 0, stream>>>(qa_emb, b2_qw, b2_qb, Qb);
  gemm_bias<<<gg, gb, 0, stream>>>(qa_emb, b2_vw, b2_vb, Vb);
  attn_fused<<<ga, 512, SMB, stream>>>(Qb, Qb, Vb, b2_gam, Ab, SEQL * DM, DM, 1, 0);
  gemm_bias<<<gg, gb, 0, stream>>>(Ab, b2_ow, b2_ob, Ob);
  add_ln<<<2048, 256, 0, stream>>>(Ob, qa_emb, DM, b2_lng, b2_lnb, HA);

  // block 3 (q = know@qw+qb broadcast; strict mask; zero_pad)
  small_pre<<<1, 256, 0, stream>>>(know, b3_qw, b3_qb, lk_w, lk_b, q3, key3);
  gemm_bias<<<gg, gb, 0, stream>>>(HQ, b3_kw, b3_kb, Qb);
  gemm_bias<<<gg, gb, 0, stream>>>(HA, b3_vw, b3_vb, Vb);
  attn_fused<<<ga, 512, SMB, stream>>>(q3, Qb, Vb, b3_gam, Ab, 0, 0, 0, 1);
  gemm_bias<<<gg, gb, 0, stream>>>(Ab, b3_ow, b3_ob, Ob);
  add_ln<<<2048, 256, 0, stream>>>(Ob, know, 0, b3_lng, b3_lnb, Hf);

  // final pooling
  final_combine<<<8192, 256, 0, stream>>>(q_emb, Hf, key3, lv_w, lv_b, (float*)d_out);
}

// Round 3
// 410.236 us; speedup vs baseline: 2.1759x; 1.5647x over previous
//
#include <hip/hip_runtime.h>
#include <stdint.h>

// Problem constants
constexpr int SEQL   = 512;
constexpr int DM     = 256;
constexpr size_t NBUFE = (size_t)8192 * DM; // 2,097,152 floats = 8MB

typedef __attribute__((ext_vector_type(4))) float f32x4;
typedef __attribute__((ext_vector_type(8))) short short8;

// ---------------- wave helpers ----------------
__device__ __forceinline__ float wred_sum(float v) {
#pragma unroll
  for (int d = 32; d >= 1; d >>= 1) v += __shfl_xor(v, d, 64);
  return v;
}
__device__ __forceinline__ unsigned bf16rne(float x) {
  unsigned b = __float_as_uint(x);
  return (b + 0x7FFFu + ((b >> 16) & 1u)) >> 16;
}

// ---------------- GEMM: C[N,256] = A[N,256] @ W[256,256] + bias ----------------
__global__ __launch_bounds__(256, 4) void gemm_bias(
    const float* __restrict__ A, const float* __restrict__ W,
    const float* __restrict__ bias, float* __restrict__ C) {
  __shared__ float As[32][68];
  __shared__ float Ws[32][68];
  const int t = threadIdx.x;
  const int tx = t & 15, ty = t >> 4;
  const int row0 = blockIdx.x << 6, col0 = blockIdx.y << 6;
  float acc[4][4];
#pragma unroll
  for (int i = 0; i < 4; ++i)
#pragma unroll
    for (int j = 0; j < 4; ++j) acc[i][j] = 0.f;

  for (int k0 = 0; k0 < 256; k0 += 32) {
#pragma unroll
    for (int hh = 0; hh < 2; ++hh) {
      int idx = (hh << 8) + t;
      int r = idx >> 3, ks = (idx & 7) << 2;
      float4 v = *(const float4*)&A[(size_t)(row0 + r) * DM + k0 + ks];
      As[ks + 0][r] = v.x; As[ks + 1][r] = v.y;
      As[ks + 2][r] = v.z; As[ks + 3][r] = v.w;
    }
#pragma unroll
    for (int hh = 0; hh < 2; ++hh) {
      int idx = (hh << 8) + t;
      int kk = idx >> 4, cs = (idx & 15) << 2;
      float4 v = *(const float4*)&W[(size_t)(k0 + kk) * DM + col0 + cs];
      *(float4*)&Ws[kk][cs] = v;
    }
    __syncthreads();
#pragma unroll
    for (int kk = 0; kk < 32; ++kk) {
      float4 a4 = *(const float4*)&As[kk][ty << 2];
      float4 w4 = *(const float4*)&Ws[kk][tx << 2];
      float aa[4] = {a4.x, a4.y, a4.z, a4.w};
      float ww[4] = {w4.x, w4.y, w4.z, w4.w};
#pragma unroll
      for (int i = 0; i < 4; ++i)
#pragma unroll
        for (int j = 0; j < 4; ++j) acc[i][j] = fmaf(aa[i], ww[j], acc[i][j]);
    }
    __syncthreads();
  }
  float4 b4 = *(const float4*)&bias[col0 + (tx << 2)];
#pragma unroll
  for (int i = 0; i < 4; ++i) {
    float4 o;
    o.x = acc[i][0] + b4.x; o.y = acc[i][1] + b4.y;
    o.z = acc[i][2] + b4.z; o.w = acc[i][3] + b4.w;
    *(float4*)&C[(size_t)(row0 + (ty << 2) + i) * DM + col0 + (tx << 2)] = o;
  }
}

// ---------------- fused attention, MFMA + wave-pair version ----------------
// WG = 512 threads = 8 waves = 4 pairs. Pair pr handles 16 query rows per
// iteration (2 iters); wave parity p owns j in [256p, 256p+256).
// Swapped QK^T: s[T] = mfma(A=K_tile, B=Q^T); lane (g,c) owns query i=i0+c and
// j = 256p + 64g + 16q + T (reg q, tile T) -> 64 scores/lane = 64 VGPR (no spill).
// K LDS rows permuted rho'(j) = 256(j>>8)+16(j&15)+4((j>>6)&3)+((j>>4)&3);
// V pre-scattered into B-fragment order so PV reads are linear ds_read_b128.
// Cross-wave (pair) reductions via LDS red slots; PV partials pair-reduced in LDS.
__global__ __launch_bounds__(512, 2) void attn_fused(
    const float* __restrict__ Q, const float* __restrict__ Kg,
    const float* __restrict__ Vg, const float* __restrict__ gam,
    float* __restrict__ O, int qsb, int qss, int peek, int zero_pad) {
  extern __shared__ char smem[];
  char* KlB = smem;                              // 32KB K bf16
  char* VfB = smem + 32768;                      // 32KB V frags [2p][8st][2dt][64][16B]
  float* accR = (float*)(smem + 65536);          // 8KB [4pr][64][8]
  float* red  = (float*)(smem + 73728);          // 2KB: 4 slots x [4pr][2p][16]
  const int tid = threadIdx.x;
  const int lane = tid & 63, wave = tid >> 6;
  const int p = wave & 1, pr = wave >> 1;
  const int b = blockIdx.x >> 3, h = blockIdx.x & 7;
  const int quarter = blockIdx.y;
  const int g = lane >> 4, c = lane & 15;

  const float* Kbase = Kg + ((size_t)b * SEQL) * DM + h * 32;
  const float* Vbase = Vg + ((size_t)b * SEQL) * DM + h * 32;
#pragma unroll
  for (int it = 0; it < 8; ++it) {
    int idx = (it << 9) + tid;
    int j = idx >> 3, c4 = idx & 7;
    float4 kv = *(const float4*)&Kbase[(size_t)j * DM + (c4 << 2)];
    int row = ((j >> 8) << 8) + ((j & 15) << 4) + (((j >> 6) & 3) << 2) + ((j >> 4) & 3);
    uint2 kp;
    kp.x = bf16rne(kv.x) | (bf16rne(kv.y) << 16);
    kp.y = bf16rne(kv.z) | (bf16rne(kv.w) << 16);
    *(uint2*)(KlB + row * 64 + c4 * 8) = kp;
    float4 vv = *(const float4*)&Vbase[(size_t)j * DM + (c4 << 2)];
    int d0 = c4 << 2, dt = d0 >> 4, dl = d0 & 15;
    int p_ = j >> 8, g_ = (j >> 6) & 3, q_ = (j >> 4) & 3, T_ = j & 15;
    int st_ = (q_ << 1) + (T_ >> 3), r_ = T_ & 7;
    char* cb = VfB + ((((p_ << 4) + (st_ << 1) + dt) << 6) + (g_ << 4) + dl) * 16 + (r_ << 1);
    *(unsigned short*)(cb + 0)  = (unsigned short)bf16rne(vv.x);
    *(unsigned short*)(cb + 16) = (unsigned short)bf16rne(vv.y);
    *(unsigned short*)(cb + 32) = (unsigned short)bf16rne(vv.z);
    *(unsigned short*)(cb + 48) = (unsigned short)bf16rne(vv.w);
  }
  __syncthreads();

  const float gh = -log1pf(__expf(gam[h]));      // -softplus(gamma_h)
  const char* kfb = KlB + (p << 14) + c * 64 + (g << 4);
  const char* vfb = VfB + (p << 14) + (lane << 4);
  const int rbase = (pr << 5) + c;

  for (int it = 0; it < 2; ++it) {
    const int i0 = (quarter << 7) + (it << 6) + (pr << 4);
    const int i_row = i0 + c;

    // ---- Q B-fragment (row i0+c, k = 8g + r), pre-scaled by 1/sqrt(32)
    const float* qr = Q + (size_t)b * qsb + (size_t)i_row * qss + h * 32 + (g << 3);
    float4 qa = *(const float4*)qr;
    float4 qb2 = *(const float4*)(qr + 4);
    const float SC = 0.17677669529663687f;
    short8 qf;
    qf[0] = (short)bf16rne(qa.x * SC); qf[1] = (short)bf16rne(qa.y * SC);
    qf[2] = (short)bf16rne(qa.z * SC); qf[3] = (short)bf16rne(qa.w * SC);
    qf[4] = (short)bf16rne(qb2.x * SC); qf[5] = (short)bf16rne(qb2.y * SC);
    qf[6] = (short)bf16rne(qb2.z * SC); qf[7] = (short)bf16rne(qb2.w * SC);

    // ---- QK^T: s[T] reg q = score(i_row, j = 256p + 64g + 16q + T)
    f32x4 s[16];
#pragma unroll
    for (int T = 0; T < 16; ++T) {
      short8 ka = *(const short8*)(kfb + (T << 10));
      s[T] = __builtin_amdgcn_mfma_f32_16x16x32_bf16(
          ka, qf, (f32x4){0.f, 0.f, 0.f, 0.f}, 0, 0, 0);
    }

    const int jb = (p << 8) + (g << 6);
    const int ilim = i_row - 1 + peek;           // mask: j <= ilim
    const int tl0 = ilim - jb, tl1 = tl0 - 16, tl2 = tl0 - 32, tl3 = tl0 - 48;

    // ---- m1 (masked max): lane -> cross-g -> cross-wave
    float m1 = -3e38f;
#pragma unroll
    for (int T = 0; T < 16; ++T) {
      m1 = fmaxf(m1, (T <= tl0) ? s[T].x : -3e38f);
      m1 = fmaxf(m1, (T <= tl1) ? s[T].y : -3e38f);
      m1 = fmaxf(m1, (T <= tl2) ? s[T].z : -3e38f);
      m1 = fmaxf(m1, (T <= tl3) ? s[T].w : -3e38f);
    }
    m1 = fmaxf(m1, __shfl_xor(m1, 16, 64));
    m1 = fmaxf(m1, __shfl_xor(m1, 32, 64));
    if (g == 0) red[rbase + (p << 4)] = m1;
    __syncthreads();
    m1 = fmaxf(red[rbase], red[rbase + 16]);

    // ---- masked-exp sums: per-q subtotals, cross-g scan, cross-wave prefix
    float T0 = 0.f, T1 = 0.f, T2 = 0.f, T3 = 0.f;
#pragma unroll
    for (int T = 0; T < 16; ++T) {
      T0 += (T <= tl0) ? __expf(s[T].x - m1) : 0.f;
      T1 += (T <= tl1) ? __expf(s[T].y - m1) : 0.f;
      T2 += (T <= tl2) ? __expf(s[T].z - m1) : 0.f;
      T3 += (T <= tl3) ? __expf(s[T].w - m1) : 0.f;
    }
    float L = T0 + T1 + T2 + T3;
    float v = L;
    float u1 = __shfl_up(v, 16, 64); v += (g >= 1) ? u1 : 0.f;
    float u2 = __shfl_up(v, 32, 64); v += (g >= 2) ? u2 : 0.f;
    float Wp = __shfl(v, c + 48, 64);            // wave-half total per row
    float X = v - L;                             // exclusive prefix within wave
    if (g == 0) red[128 + rbase + (p << 4)] = Wp;
    __syncthreads();
    const float W0 = red[128 + rbase], W1 = red[128 + rbase + 16];
    const float S1 = W0 + W1;
    const float inv1 = (S1 > 0.f) ? (1.f / S1) : 0.f;
    X += p ? W0 : 0.f;

    // ---- decay pass: 4 independent 16-chains (seeded by per-q subtotals)
    const float fi = (float)i_row;
    float r0 = X, r1 = X + T0, r2 = r1 + T1, r3 = r2 + T2;
    const float dj0 = fi - (float)jb, dj1 = dj0 - 16.f, dj2 = dj0 - 32.f, dj3 = dj0 - 48.f;
    float m2 = -3e38f;
#pragma unroll
    for (int T = 0; T < 16; ++T) {
      const float fT = (float)T;
      {
        float e = (T <= tl0) ? __expf(s[T].x - m1) : 0.f; r0 += e;
        float right = fmaxf((S1 - r0) * inv1, 0.f);
        float dist = sqrtf(right * fabsf(dj0 - fT));
        float tot = fminf(fmaxf(__expf(gh * dist), 1e-5f), 1e5f);
        float s2 = s[T].x * tot; s[T].x = s2; m2 = fmaxf(m2, s2);
      }
      {
        float e = (T <= tl1) ? __expf(s[T].y - m1) : 0.f; r1 += e;
        float right = fmaxf((S1 - r1) * inv1, 0.f);
        float dist = sqrtf(right * fabsf(dj1 - fT));
        float tot = fminf(fmaxf(__expf(gh * dist), 1e-5f), 1e5f);
        float s2 = s[T].y * tot; s[T].y = s2; m2 = fmaxf(m2, s2);
      }
      {
        float e = (T <= tl2) ? __expf(s[T].z - m1) : 0.f; r2 += e;
        float right = fmaxf((S1 - r2) * inv1, 0.f);
        float dist = sqrtf(right * fabsf(dj2 - fT));
        float tot = fminf(fmaxf(__expf(gh * dist), 1e-5f), 1e5f);
        float s2 = s[T].z * tot; s[T].z = s2; m2 = fmaxf(m2, s2);
      }
      {
        float e = (T <= tl3) ? __expf(s[T].w - m1) : 0.f; r3 += e;
        float right = fmaxf((S1 - r3) * inv1, 0.f);
        float dist = sqrtf(right * fabsf(dj3 - fT));
        float tot = fminf(fmaxf(__expf(gh * dist), 1e-5f), 1e5f);
        float s2 = s[T].w * tot; s[T].w = s2; m2 = fmaxf(m2, s2);
      }
    }
    m2 = fmaxf(m2, __shfl_xor(m2, 16, 64));
    m2 = fmaxf(m2, __shfl_xor(m2, 32, 64));
    if (g == 0) red[256 + rbase + (p << 4)] = m2;
    __syncthreads();
    m2 = fmaxf(red[256 + rbase], red[256 + rbase + 16]);

    // ---- unmasked softmax over all 512
    float S2 = 0.f;
#pragma unroll
    for (int T = 0; T < 16; ++T) {
      float ex = __expf(s[T].x - m2); s[T].x = ex; S2 += ex;
      float ey = __expf(s[T].y - m2); s[T].y = ey; S2 += ey;
      float ez = __expf(s[T].z - m2); s[T].z = ez; S2 += ez;
      float ew = __expf(s[T].w - m2); s[T].w = ew; S2 += ew;
    }
    S2 += __shfl_xor(S2, 16, 64);
    S2 += __shfl_xor(S2, 32, 64);
    if (g == 0) red[384 + rbase + (p << 4)] = S2;
    __syncthreads();
    float inv2 = 1.f / (red[384 + rbase] + red[384 + rbase + 16]);
    if (zero_pad && i_row == 0) inv2 = 0.f;      // scores[:,:,0,:] = 0

    // ---- PV partial over this wave's 256 j (8 steps x 2 d-tiles)
    f32x4 acc0 = {0.f, 0.f, 0.f, 0.f}, acc1 = {0.f, 0.f, 0.f, 0.f};
#pragma unroll
    for (int st = 0; st < 8; ++st) {
      const int q = st >> 1, Tb = (st & 1) << 3;
      short8 af;
#pragma unroll
      for (int r = 0; r < 8; ++r)
        af[r] = (short)bf16rne(s[Tb + r][q] * inv2);
      short8 vb0 = *(const short8*)(vfb + ((st << 11) + 0));
      short8 vb1 = *(const short8*)(vfb + ((st << 11) + 1024));
      acc0 = __builtin_amdgcn_mfma_f32_16x16x32_bf16(af, vb0, acc0, 0, 0, 0);
      acc1 = __builtin_amdgcn_mfma_f32_16x16x32_bf16(af, vb1, acc1, 0, 0, 0);
    }

    // ---- pair-reduce partial O and store (wave p==0 writes)
    if (p) {
      float* dst = accR + (pr << 9) + (lane << 3);
      *(f32x4*)dst = acc0;
      *(f32x4*)(dst + 4) = acc1;
    }
    __syncthreads();
    if (!p) {
      const float* src = accR + (pr << 9) + (lane << 3);
      f32x4 o0 = *(const f32x4*)src;
      f32x4 o1 = *(const f32x4*)(src + 4);
      float* orow = O + ((size_t)b * SEQL + i0 + (g << 2)) * DM + h * 32 + c;
#pragma unroll
      for (int reg = 0; reg < 4; ++reg) {
        orow[(size_t)reg * DM] = acc0[reg] + o0[reg];
        orow[(size_t)reg * DM + 16] = acc1[reg] + o1[reg];
      }
    }
  }
}

// ---------------- add + LayerNorm (one wave per row) ----------------
__global__ __launch_bounds__(256, 4) void add_ln(
    const float* __restrict__ x, const float* __restrict__ res, int res_stride,
    const float* __restrict__ g, const float* __restrict__ bb,
    float* __restrict__ out) {
  const int row = (blockIdx.x << 2) + (threadIdx.x >> 6);
  const int lane = threadIdx.x & 63;
  const size_t base = (size_t)row * DM + (lane << 2);
  float4 xv = *(const float4*)&x[base];
  float4 rv = *(const float4*)&res[(size_t)row * res_stride + (lane << 2)];
  float4 v;
  v.x = xv.x + rv.x; v.y = xv.y + rv.y; v.z = xv.z + rv.z; v.w = xv.w + rv.w;
  float s = v.x + v.y + v.z + v.w;
  s = wred_sum(s);
  const float mean = s * (1.f / 256.f);
  float4 d;
  d.x = v.x - mean; d.y = v.y - mean; d.z = v.z - mean; d.w = v.w - mean;
  float q = d.x * d.x + d.y * d.y + d.z * d.z + d.w * d.w;
  q = wred_sum(q);
  const float rstd = rsqrtf(q * (1.f / 256.f) + 1e-5f);
  float4 gv = *(const float4*)&g[lane << 2];
  float4 bv = *(const float4*)&bb[lane << 2];
  float4 o;
  o.x = fmaf(gv.x * d.x, rstd, bv.x);
  o.y = fmaf(gv.y * d.y, rstd, bv.y);
  o.z = fmaf(gv.z * d.z, rstd, bv.z);
  o.w = fmaf(gv.w * d.w, rstd, bv.w);
  *(float4*)&out[base] = o;
}

// ---------------- tiny precompute ----------------
__global__ __launch_bounds__(256) void small_pre(
    const float* __restrict__ know, const float* __restrict__ qw,
    const float* __restrict__ qb, const float* __restrict__ lkw,
    const float* __restrict__ lkb, float* __restrict__ q3,
    float* __restrict__ key3) {
  const int d = threadIdx.x;
  float acc = qb[d];
  for (int kk = 0; kk < 256; ++kk) acc = fmaf(know[kk], qw[kk * 256 + d], acc);
  q3[d] = acc;
#pragma unroll
  for (int hh = 0; hh < 8; ++hh) {
    float a = lkb[d];
#pragma unroll
    for (int kk = 0; kk < 32; ++kk)
      a = fmaf(know[hh * 32 + kk], lkw[kk * 256 + d], a);
    key3[hh * 256 + d] = 1.f / (1.f + __expf(-a));
  }
}

// ---------------- final pooling ----------------
__global__ __launch_bounds__(256, 4) void final_combine(
    const float* __restrict__ qe, const float* __restrict__ Hf,
    const float* __restrict__ key3, const float* __restrict__ lvw,
    const float* __restrict__ lvb, float* __restrict__ out) {
  __shared__ float hl[256];
  __shared__ float red[4][8];
  const int n = blockIdx.x, d = threadIdx.x;
  const int lane = d & 63, wv = d >> 6;
  hl[d] = Hf[(size_t)n * DM + d];
  const float qd = qe[(size_t)n * DM + d];
  float part[8];
#pragma unroll
  for (int hh = 0; hh < 8; ++hh) part[hh] = key3[hh * 256 + d] * qd;
#pragma unroll
  for (int hh = 0; hh < 8; ++hh) part[hh] = wred_sum(part[hh]);
  if (lane == 0) {
#pragma unroll
    for (int hh = 0; hh < 8; ++hh) red[wv][hh] = part[hh];
  }
  __syncthreads();
  float beta[8];
#pragma unroll
  for (int hh = 0; hh < 8; ++hh)
    beta[hh] = red[0][hh] + red[1][hh] + red[2][hh] + red[3][hh];
  float mb = beta[0];
#pragma unroll
  for (int hh = 1; hh < 8; ++hh) mb = fmaxf(mb, beta[hh]);
  float al[8];
  float se = 0.f;
#pragma unroll
  for (int hh = 0; hh < 8; ++hh) {
    al[hh] = __expf(beta[hh] - mb);
    se += al[hh];
  }
  const float inva = 1.f / se;
  float acc[8];
#pragma unroll
  for (int hh = 0; hh < 8; ++hh) acc[hh] = 0.f;
#pragma unroll
  for (int kk = 0; kk < 32; ++kk) {
    float w = lvw[kk * 256 + d];
#pragma unroll
    for (int hh = 0; hh < 8; ++hh) acc[hh] = fmaf(hl[hh * 32 + kk], w, acc[hh]);
  }
  const float bd = lvb[d];
  float o = 0.f;
#pragma unroll
  for (int hh = 0; hh < 8; ++hh) {
    float vv = 1.f / (1.f + __expf(-(acc[hh] + bd)));
    o = fmaf(al[hh] * inva, vv, o);
  }
  out[(size_t)n * DM + d] = o;
}

// ---------------- host launch ----------------
extern "C" void kernel_launch(void* const* d_in, const int* in_sizes, int n_in,
                              void* d_out, int out_size, void* d_ws, size_t ws_size,
                              hipStream_t stream) {
  (void)in_sizes; (void)n_in; (void)out_size; (void)ws_size;
  const float* q_emb  = (const float*)d_in[0];
  const float* qa_emb = (const float*)d_in[1];
  const float* b1_qw = (const float*)d_in[2];   const float* b1_qb = (const float*)d_in[3];
  const float* b1_vw = (const float*)d_in[4];   const float* b1_vb = (const float*)d_in[5];
  const float* b1_ow = (const float*)d_in[6];   const float* b1_ob = (const float*)d_in[7];
  const float* b1_gam = (const float*)d_in[8];
  const float* b1_lng = (const float*)d_in[9];  const float* b1_lnb = (const float*)d_in[10];
  const float* b2_qw = (const float*)d_in[11];  const float* b2_qb = (const float*)d_in[12];
  const float* b2_vw = (const float*)d_in[13];  const float* b2_vb = (const float*)d_in[14];
  const float* b2_ow = (const float*)d_in[15];  const float* b2_ob = (const float*)d_in[16];
  const float* b2_gam = (const float*)d_in[17];
  const float* b2_lng = (const float*)d_in[18]; const float* b2_lnb = (const float*)d_in[19];
  const float* b3_qw = (const float*)d_in[20];  const float* b3_qb = (const float*)d_in[21];
  const float* b3_kw = (const float*)d_in[22];  const float* b3_kb = (const float*)d_in[23];
  const float* b3_vw = (const float*)d_in[24];  const float* b3_vb = (const float*)d_in[25];
  const float* b3_ow = (const float*)d_in[26];  const float* b3_ob = (const float*)d_in[27];
  const float* b3_gam = (const float*)d_in[28];
  const float* b3_lng = (const float*)d_in[29]; const float* b3_lnb = (const float*)d_in[30];
  const float* know = (const float*)d_in[31];
  const float* lk_w = (const float*)d_in[32];   const float* lk_b = (const float*)d_in[33];
  const float* lv_w = (const float*)d_in[34];   const float* lv_b = (const float*)d_in[35];

  float* ws = (float*)d_ws;
  float* Qb = ws;
  float* Vb = ws + NBUFE;
  float* Ab = ws + 2 * NBUFE;
  float* Ob = ws + 3 * NBUFE;
  float* HQ = ws + 4 * NBUFE;
  float* HA = ws + 5 * NBUFE;
  float* Hf = ws + 6 * NBUFE;
  float* q3 = ws + 7 * NBUFE;
  float* key3 = q3 + 256;

  const int SMB = 75776;  // 32K K + 32K Vfrag + 8K accR + 2K red
  (void)hipFuncSetAttribute(reinterpret_cast<const void*>(attn_fused),
                            hipFuncAttributeMaxDynamicSharedMemorySize, SMB);

  const dim3 gg(128, 4), gb(256);
  const dim3 ga(128, 4);

  // block 1 (input q_emb; k == q)
  gemm_bias<<<gg, gb, 0, stream>>>(q_emb, b1_qw, b1_qb, Qb);
  gemm_bias<<<gg, gb, 0, stream>>>(q_emb, b1_vw, b1_vb, Vb);
  attn_fused<<<ga, 512, SMB, stream>>>(Qb, Qb, Vb, b1_gam, Ab, SEQL * DM, DM, 1, 0);
  gemm_bias<<<gg, gb, 0, stream>>>(Ab, b1_ow, b1_ob, Ob);
  add_ln<<<2048, 256, 0, stream>>>(Ob, q_emb, DM, b1_lng, b1_lnb, HQ);

  // block 2 (input qa_emb; k == q)
  gemm_bias<<<gg, gb, 0, stream>>>(qa_emb, b2_qw, b2_qb, Qb);
  gemm_bias<<<gg, gb, 0, stream>>>(qa_emb, b2_vw, b2_vb, Vb);
  attn_fused<<<ga, 512, SMB, stream>>>(Qb, Qb, Vb, b2_gam, Ab, SEQL * DM, DM, 1, 0);
  gemm_bias<<<gg, gb, 0, stream>>>(Ab, b2_ow, b2_ob, Ob);
  add_ln<<<2048, 256, 0, stream>>>(Ob, qa_emb, DM, b2_lng, b2_lnb, HA);

  // block 3 (q = know@qw+qb broadcast; strict mask; zero_pad)
  small_pre<<<1, 256, 0, stream>>>(know, b3_qw, b3_qb, lk_w, lk_b, q3, key3);
  gemm_bias<<<gg, gb, 0, stream>>>(HQ, b3_kw, b3_kb, Qb);
  gemm_bias<<<gg, gb, 0, stream>>>(HA, b3_vw, b3_vb, Vb);
  attn_fused<<<ga, 512, SMB, stream>>>(q3, Qb, Vb, b3_gam, Ab, 0, 0, 0, 1);
  gemm_bias<<<gg, gb, 0, stream>>>(Ab, b3_ow, b3_ob, Ob);
  add_ln<<<2048, 256, 0, stream>>>(Ob, know, 0, b3_lng, b3_lnb, Hf);

  // final pooling
  final_combine<<<8192, 256, 0, stream>>>(q_emb, Hf, key3, lv_w, lv_b, (float*)d_out);
}

// Round 4
// 292.630 us; speedup vs baseline: 3.0503x; 1.4019x over previous
//
#include <hip/hip_runtime.h>
#include <stdint.h>

constexpr int SEQL = 512;
constexpr int DM = 256;
constexpr float SCQ = 0.50500066f;  // sqrt(1/sqrt(32) * log2(e))

typedef __attribute__((ext_vector_type(4))) float f32x4;
typedef __attribute__((ext_vector_type(8))) short short8;
typedef unsigned short u16;

// ---------------- helpers ----------------
__device__ __forceinline__ unsigned cvt_pk_bf16(float lo, float hi) {
  unsigned r;
  asm("v_cvt_pk_bf16_f32 %0, %1, %2" : "=v"(r) : "v"(lo), "v"(hi));
  return r;
}
__device__ __forceinline__ void gload_lds16(const void* g, void* l) {
  __builtin_amdgcn_global_load_lds(
      (const __attribute__((address_space(1))) void*)g,
      (__attribute__((address_space(3))) void*)l, 16, 0, 0);
}
__device__ __forceinline__ float wred_sum(float v) {
#pragma unroll
  for (int d = 32; d >= 1; d >>= 1) v += __shfl_xor(v, d, 64);
  return v;
}

// ---------------- weight pre-transpose: Wt[n][k] bf16 ----------------
struct W9 { const float* w[9]; };
__global__ __launch_bounds__(256) void wt_pre(W9 wlist, u16* out) {
  const float* W = wlist.w[blockIdx.y];
  const int n = threadIdx.x;
  const int k8 = blockIdx.x << 3;
  float v[8];
#pragma unroll
  for (int e = 0; e < 8; ++e) v[e] = W[(size_t)(k8 + e) * 256 + n];
  unsigned u4[4];
#pragma unroll
  for (int e2 = 0; e2 < 4; ++e2) u4[e2] = cvt_pk_bf16(v[2 * e2], v[2 * e2 + 1]);
  u16* dst = out + (size_t)blockIdx.y * 65536 + (size_t)n * 256 + k8;
  *(uint4*)dst = make_uint4(u4[0], u4[1], u4[2], u4[3]);
}

// ---------------- bf16 MFMA GEMM: C[8192,256] = A[8192,256]@W + bias, xscale ----------------
struct GemmSet { const void* A; const u16* Wt; const float* bias; void* C; float scale; };
struct GemmBatch { GemmSet s[4]; };

template <int ABF16, int OBF16>
__global__ __launch_bounds__(256, 2) void gemm_mfma(GemmBatch batch) {
  extern __shared__ char lds[];
  char* Al = lds;          // 32KB: A tile 64x256 bf16, XOR-swizzled
  char* Wl = lds + 32768;  // 32KB: Wt tile 64x256 bf16, XOR-swizzled
  const GemmSet S = batch.s[blockIdx.z];
  const int tid = threadIdx.x, lane = tid & 63, wave = tid >> 6;
  const int m0 = blockIdx.x << 6, n0 = blockIdx.y << 6;

  // stage W (always bf16 global, pre-swizzled source -> linear LDS)
#pragma unroll
  for (int it = 0; it < 8; ++it) {
    int chunk = (it << 8) + tid;
    int row = chunk >> 5, cc = chunk & 31;
    gload_lds16(S.Wt + (size_t)(n0 + row) * 256 + ((cc ^ (row & 7)) << 3),
                Wl + (it << 12) + (wave << 10));
  }
  if constexpr (ABF16) {
#pragma unroll
    for (int it = 0; it < 8; ++it) {
      int chunk = (it << 8) + tid;
      int row = chunk >> 5, cc = chunk & 31;
      gload_lds16((const u16*)S.A + (size_t)(m0 + row) * 256 + ((cc ^ (row & 7)) << 3),
                  Al + (it << 12) + (wave << 10));
    }
  } else {
#pragma unroll
    for (int it = 0; it < 16; ++it) {
      int idx = (it << 8) + tid;
      int row = idx >> 6, k4 = (idx & 63) << 2;
      float4 v = *(const float4*)((const float*)S.A + (size_t)(m0 + row) * 256 + k4);
      uint2 pk2;
      pk2.x = cvt_pk_bf16(v.x, v.y);
      pk2.y = cvt_pk_bf16(v.z, v.w);
      *(uint2*)(Al + (row << 9) + ((k4 << 1) ^ ((row & 7) << 4))) = pk2;
    }
  }
  __syncthreads();

  const int g = lane >> 4, cc = lane & 15;
  const int sw = cc & 7;
  f32x4 acc[4];
#pragma unroll
  for (int j = 0; j < 4; ++j) acc[j] = (f32x4){0.f, 0.f, 0.f, 0.f};
  const char* arow = Al + (size_t)((wave << 4) + cc) * 512;
  const char* wrow = Wl + (size_t)cc * 512;
#pragma unroll
  for (int kk = 0; kk < 8; ++kk) {
    const int so = (((kk << 2) + g) ^ sw) << 4;
    short8 ka = *(const short8*)(arow + so);
#pragma unroll
    for (int j = 0; j < 4; ++j) {
      short8 kb = *(const short8*)(wrow + (j << 13) + so);
      acc[j] = __builtin_amdgcn_mfma_f32_16x16x32_bf16(ka, kb, acc[j], 0, 0, 0);
    }
  }
#pragma unroll
  for (int j = 0; j < 4; ++j) {
    float bj = S.bias[n0 + (j << 4) + cc];
#pragma unroll
    for (int r = 0; r < 4; ++r) {
      float v = (acc[j][r] + bj) * S.scale;
      size_t off = (size_t)(m0 + (wave << 4) + (g << 2) + r) * 256 + n0 + (j << 4) + cc;
      if constexpr (OBF16)
        ((u16*)S.C)[off] = (u16)cvt_pk_bf16(v, v);
      else
        ((float*)S.C)[off] = v;
    }
  }
}

// ---------------- attention chain helpers (log2 domain) ----------------
__device__ __forceinline__ void chain_max(const float (&sq)[16], int tlq, float& m1) {
  if (!__any(tlq >= 0)) return;
  if (__all(tlq >= 15)) {
#pragma unroll
    for (int T = 0; T < 16; ++T) m1 = fmaxf(m1, sq[T]);
  } else {
#pragma unroll
    for (int T = 0; T < 16; ++T) m1 = fmaxf(m1, (T <= tlq) ? sq[T] : -3e38f);
  }
}
__device__ __forceinline__ float chain_sum(const float (&sq)[16], int tlq, float m1) {
  if (!__any(tlq >= 0)) return 0.f;
  float t = 0.f;
  if (__all(tlq >= 15)) {
#pragma unroll
    for (int T = 0; T < 16; ++T) t += __builtin_amdgcn_exp2f(sq[T] - m1);
  } else {
#pragma unroll
    for (int T = 0; T < 16; ++T)
      t += (T <= tlq) ? __builtin_amdgcn_exp2f(sq[T] - m1) : 0.f;
  }
  return t;
}
__device__ __forceinline__ void chain_decay(float (&sq)[16], int tlq, float djq, float seed,
                                            float S1, float ghs, float m1, float& m2) {
  if (!__any(tlq >= 0)) {  // fully masked for this wave: tot == 1 exactly
#pragma unroll
    for (int T = 0; T < 16; ++T) m2 = fmaxf(m2, sq[T]);
    return;
  }
  float r = seed;
  if (__all(tlq >= 15)) {
#pragma unroll
    for (int T = 0; T < 16; ++T) {
      r += __builtin_amdgcn_exp2f(sq[T] - m1);
      float u = fmaxf((S1 - r) * (djq - (float)T), 0.f);
      float tot = fmaxf(__builtin_amdgcn_exp2f(ghs * __builtin_amdgcn_sqrtf(u)), 1e-5f);
      float v = sq[T] * tot;
      sq[T] = v;
      m2 = fmaxf(m2, v);
    }
  } else {
#pragma unroll
    for (int T = 0; T < 16; ++T) {
      float e = (T <= tlq) ? __builtin_amdgcn_exp2f(sq[T] - m1) : 0.f;
      r += e;
      float u = fmaxf((S1 - r) * (djq - (float)T), 0.f);
      float tot = fmaxf(__builtin_amdgcn_exp2f(ghs * __builtin_amdgcn_sqrtf(u)), 1e-5f);
      float v = sq[T] * tot;
      sq[T] = v;
      m2 = fmaxf(m2, v);
    }
  }
}
__device__ __forceinline__ void chain_pack(const float (&sq)[16], float m2, float& S2,
                                           unsigned (&pkq)[8]) {
#pragma unroll
  for (int k = 0; k < 8; ++k) {
    float pa = __builtin_amdgcn_exp2f(sq[2 * k] - m2);
    float pb = __builtin_amdgcn_exp2f(sq[2 * k + 1] - m2);
    S2 += pa + pb;
    pkq[k] = cvt_pk_bf16(pa, pb);
  }
}
__device__ __forceinline__ void pv_q(const unsigned (&pkq)[8], int qidx, const char* vfb,
                                     f32x4& acc0, f32x4& acc1) {
#pragma unroll
  for (int hf = 0; hf < 2; ++hf) {
    union { unsigned u[4]; short8 s8; } ua;
    ua.u[0] = pkq[hf * 4 + 0]; ua.u[1] = pkq[hf * 4 + 1];
    ua.u[2] = pkq[hf * 4 + 2]; ua.u[3] = pkq[hf * 4 + 3];
    const int st = qidx * 2 + hf;
    short8 vb0 = *(const short8*)(vfb + (st << 11));
    short8 vb1 = *(const short8*)(vfb + (st << 11) + 1024);
    acc0 = __builtin_amdgcn_mfma_f32_16x16x32_bf16(ua.s8, vb0, acc0, 0, 0, 0);
    acc1 = __builtin_amdgcn_mfma_f32_16x16x32_bf16(ua.s8, vb1, acc1, 0, 0, 0);
  }
}

// ---------------- fused attention (bf16 in, bf16 out) ----------------
// j = 256p + 64q + 16g + T (q = acc reg / chain, wave-aligned 64-j windows ->
// uniform chain skipping). Scores arrive pre-scaled by SC2 = log2e/sqrt(32)
// via the 0.505-scaled q/k projections; all exp are v_exp_f32 (exp2).
struct AttnSet {
  const u16* Q; const u16* K; const u16* V;
  const float* gam; u16* O;
  int qsb, qss, peek, zp;
};

__global__ __launch_bounds__(512, 4) void attn_fused(AttnSet a0, AttnSet a1) {
  extern __shared__ char smem[];
  char* KlB = smem;                      // 32KB K bf16, rho'-permuted rows
  char* VfB = smem + 32768;              // 32KB V B-fragments
  float* accR = (float*)(smem + 65536);  // 8KB pair-reduce
  float* red = (float*)(smem + 73728);   // 2KB cross-wave slots
  const int tid = threadIdx.x;
  const int lane = tid & 63, wave = tid >> 6;
  const int p = wave & 1, pr = wave >> 1;
  const AttnSet S = (blockIdx.x >> 7) ? a1 : a0;
  const int bh = blockIdx.x & 127;
  const int b = bh >> 3, h = bh & 7;
  const int y = blockIdx.y;
  const int g = lane >> 4, c = lane & 15;

  // ---- stage K via global_load_lds (row-permuted source)
  const u16* Kb = S.K + ((size_t)b * SEQL) * DM + h * 32;
#pragma unroll
  for (int it = 0; it < 4; ++it) {
    int chunk = (it << 9) + tid;
    int row = chunk >> 2, c16 = chunk & 3;
    int j = ((row >> 8) << 8) + ((row & 3) << 6) + (((row >> 2) & 3) << 4) + ((row >> 4) & 15);
    gload_lds16(Kb + (size_t)j * DM + (c16 << 3), KlB + (it << 13) + (wave << 10));
  }
  // ---- stage V scattered into PV B-fragment order
  const u16* Vb = S.V + ((size_t)b * SEQL) * DM + h * 32;
#pragma unroll
  for (int it = 0; it < 4; ++it) {
    int idx = (it << 9) + tid;
    int j = idx >> 2, dc = idx & 3, d0 = dc << 3;
    short8 v = *(const short8*)(Vb + (size_t)j * DM + d0);
    int p_ = j >> 8, q_ = (j >> 6) & 3, g_ = (j >> 4) & 3, tt = j & 15;
    int st_ = (q_ << 1) + (tt >> 3), e_ = tt & 7;
    char* base = VfB + (((p_ << 4) + (st_ << 1) + (d0 >> 4)) << 10) +
                 (((g_ << 4) + (d0 & 15)) << 4) + (e_ << 1);
    const unsigned* vu = (const unsigned*)&v;
#pragma unroll
    for (int e = 0; e < 4; ++e) {
      *(u16*)(base + (e << 5)) = (u16)(vu[e] & 0xffffu);
      *(u16*)(base + (e << 5) + 16) = (u16)(vu[e] >> 16);
    }
  }
  __syncthreads();

  const float gh2 = -log1pf(__expf(S.gam[h])) * 1.4426950408889634f;
  const char* kfb = KlB + (p << 14) + c * 64 + (g << 4);
  const char* vfb = VfB + (p << 14) + (lane << 4);
  const int rbase = (pr << 5) + c;
  const int jb0 = (p << 8) + (g << 4);

  for (int it = 0; it < 2; ++it) {
    const int sl = it ? (7 - y) : y;
    const int i0 = (sl << 6) + (pr << 4);
    const int i_row = i0 + c;
    short8 qf = *(const short8*)(S.Q + (size_t)b * S.qsb + (size_t)i_row * S.qss + h * 32 + (g << 3));

    // ---- QK^T (swapped): chain q holds j = 256p + 64q + 16g + T
    float s0a[16], s1a[16], s2a[16], s3a[16];
#pragma unroll
    for (int T = 0; T < 16; ++T) {
      short8 ka = *(const short8*)(kfb + (T << 10));
      f32x4 d = __builtin_amdgcn_mfma_f32_16x16x32_bf16(
          ka, qf, (f32x4){0.f, 0.f, 0.f, 0.f}, 0, 0, 0);
      s0a[T] = d.x; s1a[T] = d.y; s2a[T] = d.z; s3a[T] = d.w;
    }
    const int ilim = i_row - 1 + S.peek;
    const int tl0 = ilim - jb0, tl1 = tl0 - 64, tl2 = tl0 - 128, tl3 = tl0 - 192;

    // ---- P1: masked max
    float m1 = -3e38f;
    chain_max(s0a, tl0, m1); chain_max(s1a, tl1, m1);
    chain_max(s2a, tl2, m1); chain_max(s3a, tl3, m1);
    m1 = fmaxf(m1, __shfl_xor(m1, 16, 64));
    m1 = fmaxf(m1, __shfl_xor(m1, 32, 64));
    if (g == 0) red[rbase + (p << 4)] = m1;
    __syncthreads();
    m1 = fmaxf(red[rbase], red[rbase + 16]);

    // ---- P2: masked-exp sums + (q,g)-ordered prefix scan
    float T0 = chain_sum(s0a, tl0, m1), T1 = chain_sum(s1a, tl1, m1);
    float T2 = chain_sum(s2a, tl2, m1), T3 = chain_sum(s3a, tl3, m1);
    float i0v = T0, i1v = T1, i2v = T2, i3v = T3, tU;
    tU = __shfl_up(i0v, 16, 64); i0v += (g >= 1) ? tU : 0.f;
    tU = __shfl_up(i0v, 32, 64); i0v += (g >= 2) ? tU : 0.f;
    tU = __shfl_up(i1v, 16, 64); i1v += (g >= 1) ? tU : 0.f;
    tU = __shfl_up(i1v, 32, 64); i1v += (g >= 2) ? tU : 0.f;
    tU = __shfl_up(i2v, 16, 64); i2v += (g >= 1) ? tU : 0.f;
    tU = __shfl_up(i2v, 32, 64); i2v += (g >= 2) ? tU : 0.f;
    tU = __shfl_up(i3v, 16, 64); i3v += (g >= 1) ? tU : 0.f;
    tU = __shfl_up(i3v, 32, 64); i3v += (g >= 2) ? tU : 0.f;
    float U0 = __shfl(i0v, c + 48, 64), U1 = __shfl(i1v, c + 48, 64);
    float U2 = __shfl(i2v, c + 48, 64), U3 = __shfl(i3v, c + 48, 64);
    float G0 = i0v - T0, G1 = i1v - T1, G2 = i2v - T2, G3 = i3v - T3;
    if (g == 0) red[128 + rbase + (p << 4)] = U0 + U1 + U2 + U3;
    __syncthreads();
    const float W0 = red[128 + rbase], W1 = red[128 + rbase + 16];
    const float S1 = W0 + W1;
    const float inv1 = (S1 > 0.f) ? (1.f / S1) : 0.f;
    const float ghs = gh2 * __builtin_amdgcn_sqrtf(inv1);
    const float bX = p ? W0 : 0.f;

    // ---- P3: distance-decay (skip fully-masked chains: tot == 1 exactly)
    const float dj0 = (float)(i_row - jb0);
    float m2 = -3e38f;
    chain_decay(s0a, tl0, dj0, bX + G0, S1, ghs, m1, m2);
    chain_decay(s1a, tl1, dj0 - 64.f, bX + U0 + G1, S1, ghs, m1, m2);
    chain_decay(s2a, tl2, dj0 - 128.f, bX + U0 + U1 + G2, S1, ghs, m1, m2);
    chain_decay(s3a, tl3, dj0 - 192.f, bX + U0 + U1 + U2 + G3, S1, ghs, m1, m2);
    m2 = fmaxf(m2, __shfl_xor(m2, 16, 64));
    m2 = fmaxf(m2, __shfl_xor(m2, 32, 64));
    if (g == 0) red[256 + rbase + (p << 4)] = m2;
    __syncthreads();
    m2 = fmaxf(red[256 + rbase], red[256 + rbase + 16]);

    // ---- P4: unmasked softmax, pack p to bf16 (inv2 deferred to epilogue)
    unsigned pk0[8], pk1[8], pk2[8], pk3[8];
    float S2 = 0.f;
    chain_pack(s0a, m2, S2, pk0); chain_pack(s1a, m2, S2, pk1);
    chain_pack(s2a, m2, S2, pk2); chain_pack(s3a, m2, S2, pk3);
    S2 += __shfl_xor(S2, 16, 64);
    S2 += __shfl_xor(S2, 32, 64);
    if (g == 0) red[384 + rbase + (p << 4)] = S2;
    __syncthreads();
    float inv2 = 1.f / (red[384 + rbase] + red[384 + rbase + 16]);
    if (S.zp && i_row == 0) inv2 = 0.f;

    // ---- P5: PV (p from registers, V linear ds_read_b128)
    f32x4 acc0 = {0.f, 0.f, 0.f, 0.f}, acc1 = {0.f, 0.f, 0.f, 0.f};
    pv_q(pk0, 0, vfb, acc0, acc1);
    pv_q(pk1, 1, vfb, acc0, acc1);
    pv_q(pk2, 2, vfb, acc0, acc1);
    pv_q(pk3, 3, vfb, acc0, acc1);

    // ---- pair-reduce + scaled bf16 store
    if (p) {
      float* dst = accR + (pr << 9) + (lane << 3);
      *(f32x4*)dst = acc0;
      *(f32x4*)(dst + 4) = acc1;
    }
    __syncthreads();
    if (!p) {
      const float* src = accR + (pr << 9) + (lane << 3);
      f32x4 o0 = *(const f32x4*)src;
      f32x4 o1 = *(const f32x4*)(src + 4);
      float iv[4];
#pragma unroll
      for (int r = 0; r < 4; ++r) iv[r] = __shfl(inv2, (g << 2) + r, 64);
      u16* orow = S.O + ((size_t)b * SEQL + i0 + (g << 2)) * DM + h * 32 + c;
#pragma unroll
      for (int r = 0; r < 4; ++r) {
        float v0 = (acc0[r] + o0[r]) * iv[r];
        float v1 = (acc1[r] + o1[r]) * iv[r];
        orow[(size_t)r * DM] = (u16)cvt_pk_bf16(v0, v0);
        orow[(size_t)r * DM + 16] = (u16)cvt_pk_bf16(v1, v1);
      }
    }
  }
}

// ---------------- add + LayerNorm (fp32 in, bf16 out), two sets ----------------
struct LnSet { const float* x; const float* res; int rstride; const float* g; const float* b; u16* out; };
__global__ __launch_bounds__(256, 4) void add_ln(LnSet sa, LnSet sb, int rows0) {
  const int row = (blockIdx.x << 2) + (threadIdx.x >> 6);
  const bool second = row >= rows0;
  const LnSet S = second ? sb : sa;
  const int r = second ? row - rows0 : row;
  const int lane = threadIdx.x & 63;
  float4 xv = *(const float4*)&S.x[(size_t)r * DM + (lane << 2)];
  float4 rv = *(const float4*)&S.res[(size_t)r * S.rstride + (lane << 2)];
  float4 v;
  v.x = xv.x + rv.x; v.y = xv.y + rv.y; v.z = xv.z + rv.z; v.w = xv.w + rv.w;
  float s = wred_sum(v.x + v.y + v.z + v.w);
  const float mean = s * (1.f / 256.f);
  float4 d;
  d.x = v.x - mean; d.y = v.y - mean; d.z = v.z - mean; d.w = v.w - mean;
  float q = wred_sum(d.x * d.x + d.y * d.y + d.z * d.z + d.w * d.w);
  const float rstd = rsqrtf(q * (1.f / 256.f) + 1e-5f);
  float4 gv = *(const float4*)&S.g[lane << 2];
  float4 bv = *(const float4*)&S.b[lane << 2];
  float ox = fmaf(gv.x * d.x, rstd, bv.x), oy = fmaf(gv.y * d.y, rstd, bv.y);
  float oz = fmaf(gv.z * d.z, rstd, bv.z), ow = fmaf(gv.w * d.w, rstd, bv.w);
  uint2 pk2;
  pk2.x = cvt_pk_bf16(ox, oy);
  pk2.y = cvt_pk_bf16(oz, ow);
  *(uint2*)&S.out[(size_t)r * DM + (lane << 2)] = pk2;
}

// ---------------- tiny precompute: q3 (bf16, 0.505-scaled), key3 ----------------
__global__ __launch_bounds__(256) void small_pre(
    const float* know, const float* qw, const float* qb,
    const float* lkw, const float* lkb, u16* q3, float* key3) {
  const int d = threadIdx.x;
  float acc = qb[d];
  for (int kk = 0; kk < 256; ++kk) acc = fmaf(know[kk], qw[kk * 256 + d], acc);
  acc *= SCQ;
  q3[d] = (u16)cvt_pk_bf16(acc, acc);
#pragma unroll
  for (int hh = 0; hh < 8; ++hh) {
    float a = lkb[d];
#pragma unroll
    for (int kk = 0; kk < 32; ++kk)
      a = fmaf(know[hh * 32 + kk], lkw[kk * 256 + d], a);
    key3[hh * 256 + d] = 1.f / (1.f + __expf(-a));
  }
}

// ---------------- final pooling (Hf bf16) ----------------
__global__ __launch_bounds__(256, 4) void final_combine(
    const float* qe, const u16* Hf, const float* key3,
    const float* lvw, const float* lvb, float* out) {
  __shared__ float hl[256];
  __shared__ float red[4][8];
  const int n = blockIdx.x, d = threadIdx.x;
  const int lane = d & 63, wv = d >> 6;
  hl[d] = __uint_as_float(((unsigned)Hf[(size_t)n * DM + d]) << 16);
  const float qd = qe[(size_t)n * DM + d];
  float part[8];
#pragma unroll
  for (int hh = 0; hh < 8; ++hh) part[hh] = wred_sum(key3[hh * 256 + d] * qd);
  if (lane == 0) {
#pragma unroll
    for (int hh = 0; hh < 8; ++hh) red[wv][hh] = part[hh];
  }
  __syncthreads();
  float beta[8];
#pragma unroll
  for (int hh = 0; hh < 8; ++hh)
    beta[hh] = red[0][hh] + red[1][hh] + red[2][hh] + red[3][hh];
  float mb = beta[0];
#pragma unroll
  for (int hh = 1; hh < 8; ++hh) mb = fmaxf(mb, beta[hh]);
  float al[8], se = 0.f;
#pragma unroll
  for (int hh = 0; hh < 8; ++hh) { al[hh] = __expf(beta[hh] - mb); se += al[hh]; }
  const float inva = 1.f / se;
  float acc[8];
#pragma unroll
  for (int hh = 0; hh < 8; ++hh) acc[hh] = 0.f;
#pragma unroll
  for (int kk = 0; kk < 32; ++kk) {
    float w = lvw[kk * 256 + d];
#pragma unroll
    for (int hh = 0; hh < 8; ++hh) acc[hh] = fmaf(hl[hh * 32 + kk], w, acc[hh]);
  }
  const float bd = lvb[d];
  float o = 0.f;
#pragma unroll
  for (int hh = 0; hh < 8; ++hh) {
    float vv = 1.f / (1.f + __expf(-(acc[hh] + bd)));
    o = fmaf(al[hh] * inva, vv, o);
  }
  out[(size_t)n * DM + d] = o;
}

// ---------------- host launch ----------------
extern "C" void kernel_launch(void* const* d_in, const int* in_sizes, int n_in,
                              void* d_out, int out_size, void* d_ws, size_t ws_size,
                              hipStream_t stream) {
  (void)in_sizes; (void)n_in; (void)out_size; (void)ws_size;
  const float* q_emb  = (const float*)d_in[0];
  const float* qa_emb = (const float*)d_in[1];
  const float* b1_qw = (const float*)d_in[2];   const float* b1_qb = (const float*)d_in[3];
  const float* b1_vw = (const float*)d_in[4];   const float* b1_vb = (const float*)d_in[5];
  const float* b1_ow = (const float*)d_in[6];   const float* b1_ob = (const float*)d_in[7];
  const float* b1_gam = (const float*)d_in[8];
  const float* b1_lng = (const float*)d_in[9];  const float* b1_lnb = (const float*)d_in[10];
  const float* b2_qw = (const float*)d_in[11];  const float* b2_qb = (const float*)d_in[12];
  const float* b2_vw = (const float*)d_in[13];  const float* b2_vb = (const float*)d_in[14];
  const float* b2_ow = (const float*)d_in[15];  const float* b2_ob = (const float*)d_in[16];
  const float* b2_gam = (const float*)d_in[17];
  const float* b2_lng = (const float*)d_in[18]; const float* b2_lnb = (const float*)d_in[19];
  const float* b3_qw = (const float*)d_in[20];  const float* b3_qb = (const float*)d_in[21];
  const float* b3_kw = (const float*)d_in[22];  const float* b3_kb = (const float*)d_in[23];
  const float* b3_vw = (const float*)d_in[24];  const float* b3_vb = (const float*)d_in[25];
  const float* b3_ow = (const float*)d_in[26];  const float* b3_ob = (const float*)d_in[27];
  const float* b3_gam = (const float*)d_in[28];
  const float* b3_lng = (const float*)d_in[29]; const float* b3_lnb = (const float*)d_in[30];
  const float* know = (const float*)d_in[31];
  const float* lk_w = (const float*)d_in[32];   const float* lk_b = (const float*)d_in[33];
  const float* lv_w = (const float*)d_in[34];   const float* lv_b = (const float*)d_in[35];

  // workspace layout
  u16* wtb = (u16*)d_ws;                                   // 9*65536*2 = 1179648 B
  u16* q3 = (u16*)((char*)d_ws + 1179648);                 // 512 B
  float* key3 = (float*)((char*)d_ws + 1180160);           // 8192 B
  char* pool = (char*)d_ws + 1188352;
  const size_t SLOT = 2097152;  // elements per buffer (8192*256)
  u16* s0 = (u16*)pool;
  u16* s1 = s0 + SLOT; u16* s2 = s1 + SLOT; u16* s3 = s2 + SLOT;
  u16* s4 = s3 + SLOT; u16* s5 = s4 + SLOT; u16* s6 = s5 + SLOT;
  float* f0 = (float*)(pool + 7 * SLOT * 2);
  float* f1 = f0 + SLOT;

  (void)hipFuncSetAttribute((const void*)attn_fused,
                            hipFuncAttributeMaxDynamicSharedMemorySize, 75776);
  (void)hipFuncSetAttribute((const void*)&gemm_mfma<0, 1>,
                            hipFuncAttributeMaxDynamicSharedMemorySize, 65536);
  (void)hipFuncSetAttribute((const void*)&gemm_mfma<1, 0>,
                            hipFuncAttributeMaxDynamicSharedMemorySize, 65536);
  (void)hipFuncSetAttribute((const void*)&gemm_mfma<1, 1>,
                            hipFuncAttributeMaxDynamicSharedMemorySize, 65536);

  // weight transpose + tiny precompute
  W9 w9{{b1_qw, b1_vw, b1_ow, b2_qw, b2_vw, b2_ow, b3_kw, b3_vw, b3_ow}};
  wt_pre<<<dim3(32, 9), 256, 0, stream>>>(w9, wtb);
  small_pre<<<1, 256, 0, stream>>>(know, b3_qw, b3_qb, lk_w, lk_b, q3, key3);

  // q/v projections for blocks 1&2 (q-buffers pre-scaled by sqrt(SC2))
  GemmBatch g1;
  g1.s[0] = {q_emb,  wtb + 0 * 65536, b1_qb, s0, SCQ};
  g1.s[1] = {q_emb,  wtb + 1 * 65536, b1_vb, s1, 1.f};
  g1.s[2] = {qa_emb, wtb + 3 * 65536, b2_qb, s2, SCQ};
  g1.s[3] = {qa_emb, wtb + 4 * 65536, b2_vb, s3, 1.f};
  gemm_mfma<0, 1><<<dim3(128, 4, 4), 256, 65536, stream>>>(g1);

  // merged attention blocks 1&2
  AttnSet A1{s0, s0, s1, b1_gam, s4, SEQL * DM, DM, 1, 0};
  AttnSet A2{s2, s2, s3, b2_gam, s5, SEQL * DM, DM, 1, 0};
  attn_fused<<<dim3(256, 4), 512, 75776, stream>>>(A1, A2);

  // out-projections
  GemmBatch g2;
  g2.s[0] = {s4, wtb + 2 * 65536, b1_ob, f0, 1.f};
  g2.s[1] = {s5, wtb + 5 * 65536, b2_ob, f1, 1.f};
  g2.s[2] = g2.s[0]; g2.s[3] = g2.s[0];
  gemm_mfma<1, 0><<<dim3(128, 4, 2), 256, 65536, stream>>>(g2);

  // add+LN blocks 1&2 -> HQ (s1), HA (s3)
  LnSet L1{f0, q_emb, DM, b1_lng, b1_lnb, s1};
  LnSet L2{f1, qa_emb, DM, b2_lng, b2_lnb, s3};
  add_ln<<<4096, 256, 0, stream>>>(L1, L2, 8192);

  // block3 k/v projections -> Kb3 (s4, 0.505-scaled), Vb3 (s5)
  GemmBatch g3;
  g3.s[0] = {s1, wtb + 6 * 65536, b3_kb, s4, SCQ};
  g3.s[1] = {s3, wtb + 7 * 65536, b3_vb, s5, 1.f};
  g3.s[2] = g3.s[0]; g3.s[3] = g3.s[0];
  gemm_mfma<1, 1><<<dim3(128, 4, 2), 256, 65536, stream>>>(g3);

  // block3 attention (broadcast q3, strict mask, zero_pad)
  AttnSet A3{q3, s4, s5, b3_gam, s0, 0, 0, 0, 1};
  attn_fused<<<dim3(128, 4), 512, 75776, stream>>>(A3, A3);

  // block3 out-projection + add+LN -> Hf (s6)
  GemmBatch g4;
  g4.s[0] = {s0, wtb + 8 * 65536, b3_ob, f0, 1.f};
  g4.s[1] = g4.s[0]; g4.s[2] = g4.s[0]; g4.s[3] = g4.s[0];
  gemm_mfma<1, 0><<<dim3(128, 4, 1), 256, 65536, stream>>>(g4);
  LnSet L3{f0, know, 0, b3_lng, b3_lnb, s6};
  add_ln<<<2048, 256, 0, stream>>>(L3, L3, 8192);

  // final pooling
  final_combine<<<8192, 256, 0, stream>>>(q_emb, s6, key3, lv_w, lv_b, (float*)d_out);
}

// Round 6
// 232.661 us; speedup vs baseline: 3.8366x; 1.2578x over previous
//
#include <hip/hip_runtime.h>
#include <stdint.h>

constexpr int SEQL = 512;
constexpr int DM = 256;
constexpr float SCQ = 0.50500066f;  // sqrt(1/sqrt(32) * log2(e))

typedef __attribute__((ext_vector_type(4))) float f32x4;
typedef __attribute__((ext_vector_type(8))) short short8;
typedef unsigned short u16;

// ---------------- helpers ----------------
__device__ __forceinline__ unsigned cvt_pk_bf16(float lo, float hi) {
  unsigned r;
  asm("v_cvt_pk_bf16_f32 %0, %1, %2" : "=v"(r) : "v"(lo), "v"(hi));
  return r;
}
__device__ __forceinline__ void gload_lds16(const void* g, void* l) {
  __builtin_amdgcn_global_load_lds(
      (const __attribute__((address_space(1))) void*)g,
      (__attribute__((address_space(3))) void*)l, 16, 0, 0);
}
__device__ __forceinline__ float wred_sum(float v) {
#pragma unroll
  for (int d = 32; d >= 1; d >>= 1) v += __shfl_xor(v, d, 64);
  return v;
}

// ---------------- weight pre-transpose: Wt[n][k] bf16 ----------------
struct W9 { const float* w[9]; };
__global__ __launch_bounds__(256) void wt_pre(W9 wlist, u16* out) {
  const float* W = wlist.w[blockIdx.y];
  const int n = threadIdx.x;
  const int k8 = blockIdx.x << 3;
  float v[8];
#pragma unroll
  for (int e = 0; e < 8; ++e) v[e] = W[(size_t)(k8 + e) * 256 + n];
  unsigned u4[4];
#pragma unroll
  for (int e2 = 0; e2 < 4; ++e2) u4[e2] = cvt_pk_bf16(v[2 * e2], v[2 * e2 + 1]);
  u16* dst = out + (size_t)blockIdx.y * 65536 + (size_t)n * 256 + k8;
  *(uint4*)dst = make_uint4(u4[0], u4[1], u4[2], u4[3]);
}

// ---------------- bf16 MFMA GEMM: C[8192,256] = A[8192,256]@W + bias, xscale ----------------
struct GemmSet { const void* A; const u16* Wt; const float* bias; void* C; float scale; };
struct GemmBatch { GemmSet s[4]; };

template <int ABF16, int OBF16>
__global__ __launch_bounds__(256, 2) void gemm_mfma(GemmBatch batch) {
  extern __shared__ char lds[];
  char* Al = lds;          // 32KB: A tile 64x256 bf16, XOR-swizzled
  char* Wl = lds + 32768;  // 32KB: Wt tile 64x256 bf16, XOR-swizzled
  const GemmSet S = batch.s[blockIdx.z];
  const int tid = threadIdx.x, lane = tid & 63, wave = tid >> 6;
  const int m0 = blockIdx.x << 6, n0 = blockIdx.y << 6;

#pragma unroll
  for (int it = 0; it < 8; ++it) {
    int chunk = (it << 8) + tid;
    int row = chunk >> 5, cc = chunk & 31;
    gload_lds16(S.Wt + (size_t)(n0 + row) * 256 + ((cc ^ (row & 7)) << 3),
                Wl + (it << 12) + (wave << 10));
  }
  if constexpr (ABF16) {
#pragma unroll
    for (int it = 0; it < 8; ++it) {
      int chunk = (it << 8) + tid;
      int row = chunk >> 5, cc = chunk & 31;
      gload_lds16((const u16*)S.A + (size_t)(m0 + row) * 256 + ((cc ^ (row & 7)) << 3),
                  Al + (it << 12) + (wave << 10));
    }
  } else {
#pragma unroll
    for (int it = 0; it < 16; ++it) {
      int idx = (it << 8) + tid;
      int row = idx >> 6, k4 = (idx & 63) << 2;
      float4 v = *(const float4*)((const float*)S.A + (size_t)(m0 + row) * 256 + k4);
      uint2 pk2;
      pk2.x = cvt_pk_bf16(v.x, v.y);
      pk2.y = cvt_pk_bf16(v.z, v.w);
      *(uint2*)(Al + (row << 9) + ((k4 << 1) ^ ((row & 7) << 4))) = pk2;
    }
  }
  __syncthreads();

  const int g = lane >> 4, cc = lane & 15;
  const int sw = cc & 7;
  f32x4 acc[4];
#pragma unroll
  for (int j = 0; j < 4; ++j) acc[j] = (f32x4){0.f, 0.f, 0.f, 0.f};
  const char* arow = Al + (size_t)((wave << 4) + cc) * 512;
  const char* wrow = Wl + (size_t)cc * 512;
#pragma unroll
  for (int kk = 0; kk < 8; ++kk) {
    const int so = (((kk << 2) + g) ^ sw) << 4;
    short8 ka = *(const short8*)(arow + so);
#pragma unroll
    for (int j = 0; j < 4; ++j) {
      short8 kb = *(const short8*)(wrow + (j << 13) + so);
      acc[j] = __builtin_amdgcn_mfma_f32_16x16x32_bf16(ka, kb, acc[j], 0, 0, 0);
    }
  }
#pragma unroll
  for (int j = 0; j < 4; ++j) {
    float bj = S.bias[n0 + (j << 4) + cc];
#pragma unroll
    for (int r = 0; r < 4; ++r) {
      float v = (acc[j][r] + bj) * S.scale;
      size_t off = (size_t)(m0 + (wave << 4) + (g << 2) + r) * 256 + n0 + (j << 4) + cc;
      if constexpr (OBF16)
        ((u16*)S.C)[off] = (u16)cvt_pk_bf16(v, v);
      else
        ((float*)S.C)[off] = v;
    }
  }
}

// ---------------- attention chain helpers (log2 domain) ----------------
__device__ __forceinline__ void chain_max(const float (&sq)[16], int tlq, float& m1) {
  if (!__any(tlq >= 0)) return;
  if (__all(tlq >= 15)) {
#pragma unroll
    for (int T = 0; T < 16; ++T) m1 = fmaxf(m1, sq[T]);
  } else {
#pragma unroll
    for (int T = 0; T < 16; ++T) m1 = fmaxf(m1, (T <= tlq) ? sq[T] : -3e38f);
  }
}
__device__ __forceinline__ float chain_sum(const float (&sq)[16], int tlq, float m1) {
  if (!__any(tlq >= 0)) return 0.f;
  float t = 0.f;
  if (__all(tlq >= 15)) {
#pragma unroll
    for (int T = 0; T < 16; ++T) t += __builtin_amdgcn_exp2f(sq[T] - m1);
  } else {
#pragma unroll
    for (int T = 0; T < 16; ++T)
      t += (T <= tlq) ? __builtin_amdgcn_exp2f(sq[T] - m1) : 0.f;
  }
  return t;
}
__device__ __forceinline__ void chain_decay(float (&sq)[16], int tlq, float djq, float seed,
                                            float S1, float ghs, float m1, float& m2) {
  if (!__any(tlq >= 0)) {  // fully masked for this wave: tot == 1 exactly
#pragma unroll
    for (int T = 0; T < 16; ++T) m2 = fmaxf(m2, sq[T]);
    return;
  }
  float r = seed;
  if (__all(tlq >= 15)) {
#pragma unroll
    for (int T = 0; T < 16; ++T) {
      r += __builtin_amdgcn_exp2f(sq[T] - m1);
      float u = fmaxf((S1 - r) * (djq - (float)T), 0.f);
      float tot = fmaxf(__builtin_amdgcn_exp2f(ghs * __builtin_amdgcn_sqrtf(u)), 1e-5f);
      float v = sq[T] * tot;
      sq[T] = v;
      m2 = fmaxf(m2, v);
    }
  } else {
#pragma unroll
    for (int T = 0; T < 16; ++T) {
      float e = (T <= tlq) ? __builtin_amdgcn_exp2f(sq[T] - m1) : 0.f;
      r += e;
      float u = fmaxf((S1 - r) * (djq - (float)T), 0.f);
      float tot = fmaxf(__builtin_amdgcn_exp2f(ghs * __builtin_amdgcn_sqrtf(u)), 1e-5f);
      float v = sq[T] * tot;
      sq[T] = v;
      m2 = fmaxf(m2, v);
    }
  }
}
// r4-verified structure: pack ALL chains first, then PV (do NOT interleave
// pack with MFMA: r5's fused pack_pv variant failed absmax 9e-2 vs 4e-3).
__device__ __forceinline__ void chain_pack(const float (&sq)[16], float m2, float& S2,
                                           unsigned (&pkq)[8]) {
#pragma unroll
  for (int k = 0; k < 8; ++k) {
    float pa = __builtin_amdgcn_exp2f(sq[2 * k] - m2);
    float pb = __builtin_amdgcn_exp2f(sq[2 * k + 1] - m2);
    S2 += pa + pb;
    pkq[k] = cvt_pk_bf16(pa, pb);
  }
}
__device__ __forceinline__ void pv_q(const unsigned (&pkq)[8], int qidx, const char* vfb,
                                     f32x4& acc0, f32x4& acc1) {
#pragma unroll
  for (int hf = 0; hf < 2; ++hf) {
    union { unsigned u[4]; short8 s8; } ua;
    ua.u[0] = pkq[hf * 4 + 0]; ua.u[1] = pkq[hf * 4 + 1];
    ua.u[2] = pkq[hf * 4 + 2]; ua.u[3] = pkq[hf * 4 + 3];
    const int st = qidx * 2 + hf;
    short8 vb0 = *(const short8*)(vfb + (st << 11));
    short8 vb1 = *(const short8*)(vfb + (st << 11) + 1024);
    acc0 = __builtin_amdgcn_mfma_f32_16x16x32_bf16(ua.s8, vb0, acc0, 0, 0, 0);
    acc1 = __builtin_amdgcn_mfma_f32_16x16x32_bf16(ua.s8, vb1, acc1, 0, 0, 0);
  }
}

// ---------------- fused attention (bf16 in, bf16 out) ----------------
// j = 256p + 64q + 16g + T (q = acc reg / chain, wave-aligned 64-j windows ->
// uniform chain skipping). Scores arrive pre-scaled by SC2 = log2e/sqrt(32)
// via the 0.505-scaled q/k projections; all exp are v_exp_f32 (exp2).
struct AttnSet {
  const u16* Q; const u16* K; const u16* V;
  const float* gam; u16* O;
  int qsb, qss, peek, zp;
};

// (512,2): live state ~100 VGPR; min-waves=4 forced the 64-VGPR bucket and
// spilled ~420MB/dispatch to scratch (r4 post-mortem). LDS-limited to
// 2 blocks/CU regardless.
__global__ __launch_bounds__(512, 2) void attn_fused(AttnSet a0, AttnSet a1) {
  extern __shared__ char smem[];
  char* KlB = smem;                      // 32KB K bf16, rho'-permuted rows
  char* VfB = smem + 32768;              // 32KB V B-fragments
  float* accR = (float*)(smem + 65536);  // 8KB pair-reduce
  float* red = (float*)(smem + 73728);   // 2KB cross-wave slots
  const int tid = threadIdx.x;
  const int lane = tid & 63, wave = tid >> 6;
  const int p = wave & 1, pr = wave >> 1;
  const AttnSet S = (blockIdx.x >> 7) ? a1 : a0;
  const int bh = blockIdx.x & 127;
  const int b = bh >> 3, h = bh & 7;
  const int y = blockIdx.y;
  const int g = lane >> 4, c = lane & 15;

  // ---- stage K via global_load_lds (row-permuted source)
  const u16* Kb = S.K + ((size_t)b * SEQL) * DM + h * 32;
#pragma unroll
  for (int it = 0; it < 4; ++it) {
    int chunk = (it << 9) + tid;
    int row = chunk >> 2, c16 = chunk & 3;
    int j = ((row >> 8) << 8) + ((row & 3) << 6) + (((row >> 2) & 3) << 4) + ((row >> 4) & 15);
    gload_lds16(Kb + (size_t)j * DM + (c16 << 3), KlB + (it << 13) + (wave << 10));
  }
  // ---- stage V scattered into PV B-fragment order
  const u16* Vb = S.V + ((size_t)b * SEQL) * DM + h * 32;
#pragma unroll
  for (int it = 0; it < 4; ++it) {
    int idx = (it << 9) + tid;
    int j = idx >> 2, dc = idx & 3, d0 = dc << 3;
    short8 v = *(const short8*)(Vb + (size_t)j * DM + d0);
    int p_ = j >> 8, q_ = (j >> 6) & 3, g_ = (j >> 4) & 3, tt = j & 15;
    int st_ = (q_ << 1) + (tt >> 3), e_ = tt & 7;
    char* base = VfB + (((p_ << 4) + (st_ << 1) + (d0 >> 4)) << 10) +
                 (((g_ << 4) + (d0 & 15)) << 4) + (e_ << 1);
    const unsigned* vu = (const unsigned*)&v;
#pragma unroll
    for (int e = 0; e < 4; ++e) {
      *(u16*)(base + (e << 5)) = (u16)(vu[e] & 0xffffu);
      *(u16*)(base + (e << 5) + 16) = (u16)(vu[e] >> 16);
    }
  }
  __syncthreads();

  const float gh2 = -log1pf(__expf(S.gam[h])) * 1.4426950408889634f;
  const char* kfb = KlB + (p << 14) + c * 64 + (g << 4);
  const char* vfb = VfB + (p << 14) + (lane << 4);
  const int rbase = (pr << 5) + c;
  const int jb0 = (p << 8) + (g << 4);

  for (int it = 0; it < 2; ++it) {
    const int sl = it ? (7 - y) : y;
    const int i0 = (sl << 6) + (pr << 4);
    const int i_row = i0 + c;
    short8 qf = *(const short8*)(S.Q + (size_t)b * S.qsb + (size_t)i_row * S.qss + h * 32 + (g << 3));

    // ---- QK^T (swapped): chain q holds j = 256p + 64q + 16g + T
    float s0a[16], s1a[16], s2a[16], s3a[16];
#pragma unroll
    for (int T = 0; T < 16; ++T) {
      short8 ka = *(const short8*)(kfb + (T << 10));
      f32x4 d = __builtin_amdgcn_mfma_f32_16x16x32_bf16(
          ka, qf, (f32x4){0.f, 0.f, 0.f, 0.f}, 0, 0, 0);
      s0a[T] = d.x; s1a[T] = d.y; s2a[T] = d.z; s3a[T] = d.w;
    }
    const int ilim = i_row - 1 + S.peek;
    const int tl0 = ilim - jb0, tl1 = tl0 - 64, tl2 = tl0 - 128, tl3 = tl0 - 192;

    // ---- P1: masked max
    float m1 = -3e38f;
    chain_max(s0a, tl0, m1); chain_max(s1a, tl1, m1);
    chain_max(s2a, tl2, m1); chain_max(s3a, tl3, m1);
    m1 = fmaxf(m1, __shfl_xor(m1, 16, 64));
    m1 = fmaxf(m1, __shfl_xor(m1, 32, 64));
    if (g == 0) red[rbase + (p << 4)] = m1;
    __syncthreads();
    m1 = fmaxf(red[rbase], red[rbase + 16]);

    // ---- P2: masked-exp sums + (q,g)-ordered prefix scan
    float T0 = chain_sum(s0a, tl0, m1), T1 = chain_sum(s1a, tl1, m1);
    float T2 = chain_sum(s2a, tl2, m1), T3 = chain_sum(s3a, tl3, m1);
    float i0v = T0, i1v = T1, i2v = T2, i3v = T3, tU;
    tU = __shfl_up(i0v, 16, 64); i0v += (g >= 1) ? tU : 0.f;
    tU = __shfl_up(i0v, 32, 64); i0v += (g >= 2) ? tU : 0.f;
    tU = __shfl_up(i1v, 16, 64); i1v += (g >= 1) ? tU : 0.f;
    tU = __shfl_up(i1v, 32, 64); i1v += (g >= 2) ? tU : 0.f;
    tU = __shfl_up(i2v, 16, 64); i2v += (g >= 1) ? tU : 0.f;
    tU = __shfl_up(i2v, 32, 64); i2v += (g >= 2) ? tU : 0.f;
    tU = __shfl_up(i3v, 16, 64); i3v += (g >= 1) ? tU : 0.f;
    tU = __shfl_up(i3v, 32, 64); i3v += (g >= 2) ? tU : 0.f;
    float U0 = __shfl(i0v, c + 48, 64), U1 = __shfl(i1v, c + 48, 64);
    float U2 = __shfl(i2v, c + 48, 64), U3 = __shfl(i3v, c + 48, 64);
    float G0 = i0v - T0, G1 = i1v - T1, G2 = i2v - T2, G3 = i3v - T3;
    if (g == 0) red[128 + rbase + (p << 4)] = U0 + U1 + U2 + U3;
    __syncthreads();
    const float W0 = red[128 + rbase], W1 = red[128 + rbase + 16];
    const float S1 = W0 + W1;
    const float inv1 = (S1 > 0.f) ? (1.f / S1) : 0.f;
    const float ghs = gh2 * __builtin_amdgcn_sqrtf(inv1);
    const float bX = p ? W0 : 0.f;

    // ---- P3: distance-decay (skip fully-masked chains: tot == 1 exactly)
    const float dj0 = (float)(i_row - jb0);
    float m2 = -3e38f;
    chain_decay(s0a, tl0, dj0, bX + G0, S1, ghs, m1, m2);
    chain_decay(s1a, tl1, dj0 - 64.f, bX + U0 + G1, S1, ghs, m1, m2);
    chain_decay(s2a, tl2, dj0 - 128.f, bX + U0 + U1 + G2, S1, ghs, m1, m2);
    chain_decay(s3a, tl3, dj0 - 192.f, bX + U0 + U1 + U2 + G3, S1, ghs, m1, m2);
    m2 = fmaxf(m2, __shfl_xor(m2, 16, 64));
    m2 = fmaxf(m2, __shfl_xor(m2, 32, 64));
    if (g == 0) red[256 + rbase + (p << 4)] = m2;
    __syncthreads();
    m2 = fmaxf(red[256 + rbase], red[256 + rbase + 16]);

    // ---- P4: unmasked softmax, pack p to bf16 (inv2 deferred to epilogue)
    unsigned pk0[8], pk1[8], pk2[8], pk3[8];
    float S2 = 0.f;
    chain_pack(s0a, m2, S2, pk0); chain_pack(s1a, m2, S2, pk1);
    chain_pack(s2a, m2, S2, pk2); chain_pack(s3a, m2, S2, pk3);
    S2 += __shfl_xor(S2, 16, 64);
    S2 += __shfl_xor(S2, 32, 64);
    if (g == 0) red[384 + rbase + (p << 4)] = S2;
    __syncthreads();
    float inv2 = 1.f / (red[384 + rbase] + red[384 + rbase + 16]);
    if (S.zp && i_row == 0) inv2 = 0.f;

    // ---- P5: PV (p from registers, V linear ds_read_b128)
    f32x4 acc0 = {0.f, 0.f, 0.f, 0.f}, acc1 = {0.f, 0.f, 0.f, 0.f};
    pv_q(pk0, 0, vfb, acc0, acc1);
    pv_q(pk1, 1, vfb, acc0, acc1);
    pv_q(pk2, 2, vfb, acc0, acc1);
    pv_q(pk3, 3, vfb, acc0, acc1);

    // ---- pair-reduce + scaled bf16 store
    if (p) {
      float* dst = accR + (pr << 9) + (lane << 3);
      *(f32x4*)dst = acc0;
      *(f32x4*)(dst + 4) = acc1;
    }
    __syncthreads();
    if (!p) {
      const float* src = accR + (pr << 9) + (lane << 3);
      f32x4 o0 = *(const f32x4*)src;
      f32x4 o1 = *(const f32x4*)(src + 4);
      float iv[4];
#pragma unroll
      for (int r = 0; r < 4; ++r) iv[r] = __shfl(inv2, (g << 2) + r, 64);
      u16* orow = S.O + ((size_t)b * SEQL + i0 + (g << 2)) * DM + h * 32 + c;
#pragma unroll
      for (int r = 0; r < 4; ++r) {
        float v0 = (acc0[r] + o0[r]) * iv[r];
        float v1 = (acc1[r] + o1[r]) * iv[r];
        orow[(size_t)r * DM] = (u16)cvt_pk_bf16(v0, v0);
        orow[(size_t)r * DM + 16] = (u16)cvt_pk_bf16(v1, v1);
      }
    }
  }
}

// ---------------- add + LayerNorm (fp32 in, bf16 out), two sets ----------------
struct LnSet { const float* x; const float* res; int rstride; const float* g; const float* b; u16* out; };
__global__ __launch_bounds__(256, 4) void add_ln(LnSet sa, LnSet sb, int rows0) {
  const int row = (blockIdx.x << 2) + (threadIdx.x >> 6);
  const bool second = row >= rows0;
  const LnSet S = second ? sb : sa;
  const int r = second ? row - rows0 : row;
  const int lane = threadIdx.x & 63;
  float4 xv = *(const float4*)&S.x[(size_t)r * DM + (lane << 2)];
  float4 rv = *(const float4*)&S.res[(size_t)r * S.rstride + (lane << 2)];
  float4 v;
  v.x = xv.x + rv.x; v.y = xv.y + rv.y; v.z = xv.z + rv.z; v.w = xv.w + rv.w;
  float s = wred_sum(v.x + v.y + v.z + v.w);
  const float mean = s * (1.f / 256.f);
  float4 d;
  d.x = v.x - mean; d.y = v.y - mean; d.z = v.z - mean; d.w = v.w - mean;
  float q = wred_sum(d.x * d.x + d.y * d.y + d.z * d.z + d.w * d.w);
  const float rstd = rsqrtf(q * (1.f / 256.f) + 1e-5f);
  float4 gv = *(const float4*)&S.g[lane << 2];
  float4 bv = *(const float4*)&S.b[lane << 2];
  float ox = fmaf(gv.x * d.x, rstd, bv.x), oy = fmaf(gv.y * d.y, rstd, bv.y);
  float oz = fmaf(gv.z * d.z, rstd, bv.z), ow = fmaf(gv.w * d.w, rstd, bv.w);
  uint2 pk2;
  pk2.x = cvt_pk_bf16(ox, oy);
  pk2.y = cvt_pk_bf16(oz, ow);
  *(uint2*)&S.out[(size_t)r * DM + (lane << 2)] = pk2;
}

// ---------------- tiny precompute: q3 (bf16, 0.505-scaled), key3 ----------------
__global__ __launch_bounds__(256) void small_pre(
    const float* know, const float* qw, const float* qb,
    const float* lkw, const float* lkb, u16* q3, float* key3) {
  const int d = threadIdx.x;
  float acc = qb[d];
  for (int kk = 0; kk < 256; ++kk) acc = fmaf(know[kk], qw[kk * 256 + d], acc);
  acc *= SCQ;
  q3[d] = (u16)cvt_pk_bf16(acc, acc);
#pragma unroll
  for (int hh = 0; hh < 8; ++hh) {
    float a = lkb[d];
#pragma unroll
    for (int kk = 0; kk < 32; ++kk)
      a = fmaf(know[hh * 32 + kk], lkw[kk * 256 + d], a);
    key3[hh * 256 + d] = 1.f / (1.f + __expf(-a));
  }
}

// ---------------- final pooling (Hf bf16) ----------------
__global__ __launch_bounds__(256, 4) void final_combine(
    const float* qe, const u16* Hf, const float* key3,
    const float* lvw, const float* lvb, float* out) {
  __shared__ float hl[256];
  __shared__ float red[4][8];
  const int n = blockIdx.x, d = threadIdx.x;
  const int lane = d & 63, wv = d >> 6;
  hl[d] = __uint_as_float(((unsigned)Hf[(size_t)n * DM + d]) << 16);
  const float qd = qe[(size_t)n * DM + d];
  float part[8];
#pragma unroll
  for (int hh = 0; hh < 8; ++hh) part[hh] = wred_sum(key3[hh * 256 + d] * qd);
  if (lane == 0) {
#pragma unroll
    for (int hh = 0; hh < 8; ++hh) red[wv][hh] = part[hh];
  }
  __syncthreads();
  float beta[8];
#pragma unroll
  for (int hh = 0; hh < 8; ++hh)
    beta[hh] = red[0][hh] + red[1][hh] + red[2][hh] + red[3][hh];
  float mb = beta[0];
#pragma unroll
  for (int hh = 1; hh < 8; ++hh) mb = fmaxf(mb, beta[hh]);
  float al[8], se = 0.f;
#pragma unroll
  for (int hh = 0; hh < 8; ++hh) { al[hh] = __expf(beta[hh] - mb); se += al[hh]; }
  const float inva = 1.f / se;
  float acc[8];
#pragma unroll
  for (int hh = 0; hh < 8; ++hh) acc[hh] = 0.f;
#pragma unroll
  for (int kk = 0; kk < 32; ++kk) {
    float w = lvw[kk * 256 + d];
#pragma unroll
    for (int hh = 0; hh < 8; ++hh) acc[hh] = fmaf(hl[hh * 32 + kk], w, acc[hh]);
  }
  const float bd = lvb[d];
  float o = 0.f;
#pragma unroll
  for (int hh = 0; hh < 8; ++hh) {
    float vv = 1.f / (1.f + __expf(-(acc[hh] + bd)));
    o = fmaf(al[hh] * inva, vv, o);
  }
  out[(size_t)n * DM + d] = o;
}

// ---------------- host launch ----------------
extern "C" void kernel_launch(void* const* d_in, const int* in_sizes, int n_in,
                              void* d_out, int out_size, void* d_ws, size_t ws_size,
                              hipStream_t stream) {
  (void)in_sizes; (void)n_in; (void)out_size; (void)ws_size;
  const float* q_emb  = (const float*)d_in[0];
  const float* qa_emb = (const float*)d_in[1];
  const float* b1_qw = (const float*)d_in[2];   const float* b1_qb = (const float*)d_in[3];
  const float* b1_vw = (const float*)d_in[4];   const float* b1_vb = (const float*)d_in[5];
  const float* b1_ow = (const float*)d_in[6];   const float* b1_ob = (const float*)d_in[7];
  const float* b1_gam = (const float*)d_in[8];
  const float* b1_lng = (const float*)d_in[9];  const float* b1_lnb = (const float*)d_in[10];
  const float* b2_qw = (const float*)d_in[11];  const float* b2_qb = (const float*)d_in[12];
  const float* b2_vw = (const float*)d_in[13];  const float* b2_vb = (const float*)d_in[14];
  const float* b2_ow = (const float*)d_in[15];  const float* b2_ob = (const float*)d_in[16];
  const float* b2_gam = (const float*)d_in[17];
  const float* b2_lng = (const float*)d_in[18]; const float* b2_lnb = (const float*)d_in[19];
  const float* b3_qw = (const float*)d_in[20];  const float* b3_qb = (const float*)d_in[21];
  const float* b3_kw = (const float*)d_in[22];  const float* b3_kb = (const float*)d_in[23];
  const float* b3_vw = (const float*)d_in[24];  const float* b3_vb = (const float*)d_in[25];
  const float* b3_ow = (const float*)d_in[26];  const float* b3_ob = (const float*)d_in[27];
  const float* b3_gam = (const float*)d_in[28];
  const float* b3_lng = (const float*)d_in[29]; const float* b3_lnb = (const float*)d_in[30];
  const float* know = (const float*)d_in[31];
  const float* lk_w = (const float*)d_in[32];   const float* lk_b = (const float*)d_in[33];
  const float* lv_w = (const float*)d_in[34];   const float* lv_b = (const float*)d_in[35];

  // workspace layout
  u16* wtb = (u16*)d_ws;                                   // 9*65536*2 = 1179648 B
  u16* q3 = (u16*)((char*)d_ws + 1179648);                 // 512 B
  float* key3 = (float*)((char*)d_ws + 1180160);           // 8192 B
  char* pool = (char*)d_ws + 1188352;
  const size_t SLOT = 2097152;  // elements per buffer (8192*256)
  u16* s0 = (u16*)pool;
  u16* s1 = s0 + SLOT; u16* s2 = s1 + SLOT; u16* s3 = s2 + SLOT;
  u16* s4 = s3 + SLOT; u16* s5 = s4 + SLOT; u16* s6 = s5 + SLOT;
  float* f0 = (float*)(pool + 7 * SLOT * 2);
  float* f1 = f0 + SLOT;

  (void)hipFuncSetAttribute((const void*)attn_fused,
                            hipFuncAttributeMaxDynamicSharedMemorySize, 75776);
  (void)hipFuncSetAttribute((const void*)&gemm_mfma<0, 1>,
                            hipFuncAttributeMaxDynamicSharedMemorySize, 65536);
  (void)hipFuncSetAttribute((const void*)&gemm_mfma<1, 0>,
                            hipFuncAttributeMaxDynamicSharedMemorySize, 65536);
  (void)hipFuncSetAttribute((const void*)&gemm_mfma<1, 1>,
                            hipFuncAttributeMaxDynamicSharedMemorySize, 65536);

  // weight transpose + tiny precompute
  W9 w9{{b1_qw, b1_vw, b1_ow, b2_qw, b2_vw, b2_ow, b3_kw, b3_vw, b3_ow}};
  wt_pre<<<dim3(32, 9), 256, 0, stream>>>(w9, wtb);
  small_pre<<<1, 256, 0, stream>>>(know, b3_qw, b3_qb, lk_w, lk_b, q3, key3);

  // q/v projections for blocks 1&2 (q-buffers pre-scaled by sqrt(SC2))
  GemmBatch g1;
  g1.s[0] = {q_emb,  wtb + 0 * 65536, b1_qb, s0, SCQ};
  g1.s[1] = {q_emb,  wtb + 1 * 65536, b1_vb, s1, 1.f};
  g1.s[2] = {qa_emb, wtb + 3 * 65536, b2_qb, s2, SCQ};
  g1.s[3] = {qa_emb, wtb + 4 * 65536, b2_vb, s3, 1.f};
  gemm_mfma<0, 1><<<dim3(128, 4, 4), 256, 65536, stream>>>(g1);

  // merged attention blocks 1&2
  AttnSet A1{s0, s0, s1, b1_gam, s4, SEQL * DM, DM, 1, 0};
  AttnSet A2{s2, s2, s3, b2_gam, s5, SEQL * DM, DM, 1, 0};
  attn_fused<<<dim3(256, 4), 512, 75776, stream>>>(A1, A2);

  // out-projections
  GemmBatch g2;
  g2.s[0] = {s4, wtb + 2 * 65536, b1_ob, f0, 1.f};
  g2.s[1] = {s5, wtb + 5 * 65536, b2_ob, f1, 1.f};
  g2.s[2] = g2.s[0]; g2.s[3] = g2.s[0];
  gemm_mfma<1, 0><<<dim3(128, 4, 2), 256, 65536, stream>>>(g2);

  // add+LN blocks 1&2 -> HQ (s1), HA (s3)
  LnSet L1{f0, q_emb, DM, b1_lng, b1_lnb, s1};
  LnSet L2{f1, qa_emb, DM, b2_lng, b2_lnb, s3};
  add_ln<<<4096, 256, 0, stream>>>(L1, L2, 8192);

  // block3 k/v projections -> Kb3 (s4, 0.505-scaled), Vb3 (s5)
  GemmBatch g3;
  g3.s[0] = {s1, wtb + 6 * 65536, b3_kb, s4, SCQ};
  g3.s[1] = {s3, wtb + 7 * 65536, b3_vb, s5, 1.f};
  g3.s[2] = g3.s[0]; g3.s[3] = g3.s[0];
  gemm_mfma<1, 1><<<dim3(128, 4, 2), 256, 65536, stream>>>(g3);

  // block3 attention (broadcast q3, strict mask, zero_pad)
  AttnSet A3{q3, s4, s5, b3_gam, s0, 0, 0, 0, 1};
  attn_fused<<<dim3(128, 4), 512, 75776, stream>>>(A3, A3);

  // block3 out-projection + add+LN -> Hf (s6)
  GemmBatch g4;
  g4.s[0] = {s0, wtb + 8 * 65536, b3_ob, f0, 1.f};
  g4.s[1] = g4.s[0]; g4.s[2] = g4.s[0]; g4.s[3] = g4.s[0];
  gemm_mfma<1, 0><<<dim3(128, 4, 1), 256, 65536, stream>>>(g4);
  LnSet L3{f0, know, 0, b3_lng, b3_lnb, s6};
  add_ln<<<2048, 256, 0, stream>>>(L3, L3, 8192);

  // final pooling
  final_combine<<<8192, 256, 0, stream>>>(q_emb, s6, key3, lv_w, lv_b, (float*)d_out);
}

// Round 7
// 216.951 us; speedup vs baseline: 4.1144x; 1.0724x over previous
//
#include <hip/hip_runtime.h>
#include <stdint.h>

constexpr int SEQL = 512;
constexpr int DM = 256;
constexpr float SCQ = 0.50500066f;  // sqrt(1/sqrt(32) * log2(e))

typedef __attribute__((ext_vector_type(4))) float f32x4;
typedef __attribute__((ext_vector_type(8))) short short8;
typedef unsigned short u16;

// ---------------- helpers ----------------
__device__ __forceinline__ unsigned cvt_pk_bf16(float lo, float hi) {
  unsigned r;
  asm("v_cvt_pk_bf16_f32 %0, %1, %2" : "=v"(r) : "v"(lo), "v"(hi));
  return r;
}
__device__ __forceinline__ void gload_lds16(const void* g, void* l) {
  __builtin_amdgcn_global_load_lds(
      (const __attribute__((address_space(1))) void*)g,
      (__attribute__((address_space(3))) void*)l, 16, 0, 0);
}
__device__ __forceinline__ float wred_sum(float v) {
#pragma unroll
  for (int d = 32; d >= 1; d >>= 1) v += __shfl_xor(v, d, 64);
  return v;
}

// ---------------- weight pre-transpose: Wt[n][k] bf16 ----------------
struct W9 { const float* w[9]; };
__global__ __launch_bounds__(256) void wt_pre(W9 wlist, u16* out) {
  const float* W = wlist.w[blockIdx.y];
  const int n = threadIdx.x;
  const int k8 = blockIdx.x << 3;
  float v[8];
#pragma unroll
  for (int e = 0; e < 8; ++e) v[e] = W[(size_t)(k8 + e) * 256 + n];
  unsigned u4[4];
#pragma unroll
  for (int e2 = 0; e2 < 4; ++e2) u4[e2] = cvt_pk_bf16(v[2 * e2], v[2 * e2 + 1]);
  u16* dst = out + (size_t)blockIdx.y * 65536 + (size_t)n * 256 + k8;
  *(uint4*)dst = make_uint4(u4[0], u4[1], u4[2], u4[3]);
}

// ---------------- bf16 MFMA GEMM: C[8192,256] = A[8192,256]@W + bias, xscale ----------------
struct GemmSet { const void* A; const u16* Wt; const float* bias; void* C; float scale; };
struct GemmBatch { GemmSet s[4]; };

template <int ABF16, int OBF16>
__global__ __launch_bounds__(256, 2) void gemm_mfma(GemmBatch batch) {
  extern __shared__ char lds[];
  char* Al = lds;          // 32KB: A tile 64x256 bf16, XOR-swizzled
  char* Wl = lds + 32768;  // 32KB: Wt tile 64x256 bf16, XOR-swizzled
  const GemmSet S = batch.s[blockIdx.z];
  const int tid = threadIdx.x, lane = tid & 63, wave = tid >> 6;
  const int m0 = blockIdx.x << 6, n0 = blockIdx.y << 6;

#pragma unroll
  for (int it = 0; it < 8; ++it) {
    int chunk = (it << 8) + tid;
    int row = chunk >> 5, cc = chunk & 31;
    gload_lds16(S.Wt + (size_t)(n0 + row) * 256 + ((cc ^ (row & 7)) << 3),
                Wl + (it << 12) + (wave << 10));
  }
  if constexpr (ABF16) {
#pragma unroll
    for (int it = 0; it < 8; ++it) {
      int chunk = (it << 8) + tid;
      int row = chunk >> 5, cc = chunk & 31;
      gload_lds16((const u16*)S.A + (size_t)(m0 + row) * 256 + ((cc ^ (row & 7)) << 3),
                  Al + (it << 12) + (wave << 10));
    }
  } else {
#pragma unroll
    for (int it = 0; it < 16; ++it) {
      int idx = (it << 8) + tid;
      int row = idx >> 6, k4 = (idx & 63) << 2;
      float4 v = *(const float4*)((const float*)S.A + (size_t)(m0 + row) * 256 + k4);
      uint2 pk2;
      pk2.x = cvt_pk_bf16(v.x, v.y);
      pk2.y = cvt_pk_bf16(v.z, v.w);
      *(uint2*)(Al + (row << 9) + ((k4 << 1) ^ ((row & 7) << 4))) = pk2;
    }
  }
  __syncthreads();

  const int g = lane >> 4, cc = lane & 15;
  const int sw = cc & 7;
  f32x4 acc[4];
#pragma unroll
  for (int j = 0; j < 4; ++j) acc[j] = (f32x4){0.f, 0.f, 0.f, 0.f};
  const char* arow = Al + (size_t)((wave << 4) + cc) * 512;
  const char* wrow = Wl + (size_t)cc * 512;
#pragma unroll
  for (int kk = 0; kk < 8; ++kk) {
    const int so = (((kk << 2) + g) ^ sw) << 4;
    short8 ka = *(const short8*)(arow + so);
#pragma unroll
    for (int j = 0; j < 4; ++j) {
      short8 kb = *(const short8*)(wrow + (j << 13) + so);
      acc[j] = __builtin_amdgcn_mfma_f32_16x16x32_bf16(ka, kb, acc[j], 0, 0, 0);
    }
  }
#pragma unroll
  for (int j = 0; j < 4; ++j) {
    float bj = S.bias[n0 + (j << 4) + cc];
#pragma unroll
    for (int r = 0; r < 4; ++r) {
      float v = (acc[j][r] + bj) * S.scale;
      size_t off = (size_t)(m0 + (wave << 4) + (g << 2) + r) * 256 + n0 + (j << 4) + cc;
      if constexpr (OBF16)
        ((u16*)S.C)[off] = (u16)cvt_pk_bf16(v, v);
      else
        ((float*)S.C)[off] = v;
    }
  }
}

// ---------------- attention chain helpers (log2 domain, NO max-subtraction) ----------------
// m1 = m2 = 0 is numerically safe for this problem: scores are pre-scaled by
// log2e/sqrt(32) and distributed ~N(0,1.3) (sigma=0.06 weights, LN'd inputs),
// so exp2 args stay in [-10,10] with huge fp32 margin.
__device__ __forceinline__ float chain_sum(const float (&sq)[16], int tlq) {
  if (!__any(tlq >= 0)) return 0.f;
  float t = 0.f;
  if (__all(tlq >= 15)) {
#pragma unroll
    for (int T = 0; T < 16; ++T) t += __builtin_amdgcn_exp2f(sq[T]);
  } else {
#pragma unroll
    for (int T = 0; T < 16; ++T)
      t += (T <= tlq) ? __builtin_amdgcn_exp2f(sq[T]) : 0.f;
  }
  return t;
}
__device__ __forceinline__ void chain_decay(float (&sq)[16], int tlq, float djq, float seed,
                                            float S1, float ghs) {
  if (!__any(tlq >= 0)) return;  // fully masked for this wave: tot == 1 exactly
  float r = seed;
  if (__all(tlq >= 15)) {
#pragma unroll
    for (int T = 0; T < 16; ++T) {
      r += __builtin_amdgcn_exp2f(sq[T]);
      float u = fmaxf((S1 - r) * (djq - (float)T), 0.f);
      float tot = fmaxf(__builtin_amdgcn_exp2f(ghs * __builtin_amdgcn_sqrtf(u)), 1e-5f);
      sq[T] *= tot;  // ghs <= 0 so tot <= 1: reference's 1e5 upper clip never active
    }
  } else {
#pragma unroll
    for (int T = 0; T < 16; ++T) {
      float e = (T <= tlq) ? __builtin_amdgcn_exp2f(sq[T]) : 0.f;
      r += e;
      float u = fmaxf((S1 - r) * (djq - (float)T), 0.f);
      float tot = fmaxf(__builtin_amdgcn_exp2f(ghs * __builtin_amdgcn_sqrtf(u)), 1e-5f);
      sq[T] *= tot;
    }
  }
}
// r4-verified structure: pack ALL chains first, then PV (do NOT interleave
// pack with MFMA: r5's fused pack_pv variant failed absmax 9e-2 vs 4e-3).
__device__ __forceinline__ void chain_pack(const float (&sq)[16], float& S2,
                                           unsigned (&pkq)[8]) {
#pragma unroll
  for (int k = 0; k < 8; ++k) {
    float pa = __builtin_amdgcn_exp2f(sq[2 * k]);
    float pb = __builtin_amdgcn_exp2f(sq[2 * k + 1]);
    S2 += pa + pb;
    pkq[k] = cvt_pk_bf16(pa, pb);
  }
}
__device__ __forceinline__ void pv_q(const unsigned (&pkq)[8], int qidx, const char* vfb,
                                     f32x4& acc0, f32x4& acc1) {
#pragma unroll
  for (int hf = 0; hf < 2; ++hf) {
    union { unsigned u[4]; short8 s8; } ua;
    ua.u[0] = pkq[hf * 4 + 0]; ua.u[1] = pkq[hf * 4 + 1];
    ua.u[2] = pkq[hf * 4 + 2]; ua.u[3] = pkq[hf * 4 + 3];
    const int st = qidx * 2 + hf;
    short8 vb0 = *(const short8*)(vfb + (st << 11));
    short8 vb1 = *(const short8*)(vfb + (st << 11) + 1024);
    acc0 = __builtin_amdgcn_mfma_f32_16x16x32_bf16(ua.s8, vb0, acc0, 0, 0, 0);
    acc1 = __builtin_amdgcn_mfma_f32_16x16x32_bf16(ua.s8, vb1, acc1, 0, 0, 0);
  }
}

// ---------------- fused attention (bf16 in, bf16 out) ----------------
// j = 256p + 64q + 16g + T. 2 barriers per iteration:
//   B1 after S1-partials (prefix scan seeds + decay scale need全wave S1)
//   B2 after {S2-partials written, PV done, accR written} -> p=0 reads
//      inv2 + accR and stores. PV needs no inv2 (applied at store), so the
//      old S2-barrier merges with the pair-reduce barrier.
struct AttnSet {
  const u16* Q; const u16* K; const u16* V;
  const float* gam; u16* O;
  int qsb, qss, peek, zp;
};

// (512,2): live state ~90-100 VGPR; min-waves=4 forces the 64-VGPR bucket and
// spills ~420MB/dispatch to scratch (r4 post-mortem). LDS-limited to
// 2 blocks/CU regardless.
__global__ __launch_bounds__(512, 2) void attn_fused(AttnSet a0, AttnSet a1) {
  extern __shared__ char smem[];
  char* KlB = smem;                      // 32KB K bf16, rho'-permuted rows
  char* VfB = smem + 32768;              // 32KB V B-fragments
  float* accR = (float*)(smem + 65536);  // 8KB pair-reduce
  float* red = (float*)(smem + 73728);   // 1KB cross-wave slots (S1, S2)
  const int tid = threadIdx.x;
  const int lane = tid & 63, wave = tid >> 6;
  const int p = wave & 1, pr = wave >> 1;
  const AttnSet S = (blockIdx.x >> 7) ? a1 : a0;
  const int bh = blockIdx.x & 127;
  const int b = bh >> 3, h = bh & 7;
  const int y = blockIdx.y;
  const int g = lane >> 4, c = lane & 15;

  // ---- stage K via global_load_lds (row-permuted source)
  const u16* Kb = S.K + ((size_t)b * SEQL) * DM + h * 32;
#pragma unroll
  for (int it = 0; it < 4; ++it) {
    int chunk = (it << 9) + tid;
    int row = chunk >> 2, c16 = chunk & 3;
    int j = ((row >> 8) << 8) + ((row & 3) << 6) + (((row >> 2) & 3) << 4) + ((row >> 4) & 15);
    gload_lds16(Kb + (size_t)j * DM + (c16 << 3), KlB + (it << 13) + (wave << 10));
  }
  // ---- stage V scattered into PV B-fragment order
  const u16* Vb = S.V + ((size_t)b * SEQL) * DM + h * 32;
#pragma unroll
  for (int it = 0; it < 4; ++it) {
    int idx = (it << 9) + tid;
    int j = idx >> 2, dc = idx & 3, d0 = dc << 3;
    short8 v = *(const short8*)(Vb + (size_t)j * DM + d0);
    int p_ = j >> 8, q_ = (j >> 6) & 3, g_ = (j >> 4) & 3, tt = j & 15;
    int st_ = (q_ << 1) + (tt >> 3), e_ = tt & 7;
    char* base = VfB + (((p_ << 4) + (st_ << 1) + (d0 >> 4)) << 10) +
                 (((g_ << 4) + (d0 & 15)) << 4) + (e_ << 1);
    const unsigned* vu = (const unsigned*)&v;
#pragma unroll
    for (int e = 0; e < 4; ++e) {
      *(u16*)(base + (e << 5)) = (u16)(vu[e] & 0xffffu);
      *(u16*)(base + (e << 5) + 16) = (u16)(vu[e] >> 16);
    }
  }
  __syncthreads();

  const float gh2 = -log1pf(__expf(S.gam[h])) * 1.4426950408889634f;
  const char* kfb = KlB + (p << 14) + c * 64 + (g << 4);
  const char* vfb = VfB + (p << 14) + (lane << 4);
  const int rbase = (pr << 5) + c;
  const int jb0 = (p << 8) + (g << 4);

  for (int it = 0; it < 2; ++it) {
    const int sl = it ? (7 - y) : y;
    const int i0 = (sl << 6) + (pr << 4);
    const int i_row = i0 + c;
    short8 qf = *(const short8*)(S.Q + (size_t)b * S.qsb + (size_t)i_row * S.qss + h * 32 + (g << 3));

    // ---- QK^T (swapped): chain q holds j = 256p + 64q + 16g + T
    float s0a[16], s1a[16], s2a[16], s3a[16];
#pragma unroll
    for (int T = 0; T < 16; ++T) {
      short8 ka = *(const short8*)(kfb + (T << 10));
      f32x4 d = __builtin_amdgcn_mfma_f32_16x16x32_bf16(
          ka, qf, (f32x4){0.f, 0.f, 0.f, 0.f}, 0, 0, 0);
      s0a[T] = d.x; s1a[T] = d.y; s2a[T] = d.z; s3a[T] = d.w;
    }
    const int ilim = i_row - 1 + S.peek;
    const int tl0 = ilim - jb0, tl1 = tl0 - 64, tl2 = tl0 - 128, tl3 = tl0 - 192;

    // ---- P2: masked-exp sums + (q,g)-ordered prefix scan
    float T0 = chain_sum(s0a, tl0), T1 = chain_sum(s1a, tl1);
    float T2 = chain_sum(s2a, tl2), T3 = chain_sum(s3a, tl3);
    float i0v = T0, i1v = T1, i2v = T2, i3v = T3, tU;
    tU = __shfl_up(i0v, 16, 64); i0v += (g >= 1) ? tU : 0.f;
    tU = __shfl_up(i0v, 32, 64); i0v += (g >= 2) ? tU : 0.f;
    tU = __shfl_up(i1v, 16, 64); i1v += (g >= 1) ? tU : 0.f;
    tU = __shfl_up(i1v, 32, 64); i1v += (g >= 2) ? tU : 0.f;
    tU = __shfl_up(i2v, 16, 64); i2v += (g >= 1) ? tU : 0.f;
    tU = __shfl_up(i2v, 32, 64); i2v += (g >= 2) ? tU : 0.f;
    tU = __shfl_up(i3v, 16, 64); i3v += (g >= 1) ? tU : 0.f;
    tU = __shfl_up(i3v, 32, 64); i3v += (g >= 2) ? tU : 0.f;
    float U0 = __shfl(i0v, c + 48, 64), U1 = __shfl(i1v, c + 48, 64);
    float U2 = __shfl(i2v, c + 48, 64), U3 = __shfl(i3v, c + 48, 64);
    float G0 = i0v - T0, G1 = i1v - T1, G2 = i2v - T2, G3 = i3v - T3;
    if (g == 0) red[rbase + (p << 4)] = U0 + U1 + U2 + U3;
    __syncthreads();  // B1
    const float W0 = red[rbase], W1 = red[rbase + 16];
    const float S1 = W0 + W1;
    const float inv1 = (S1 > 0.f) ? (1.f / S1) : 0.f;
    const float ghs = gh2 * __builtin_amdgcn_sqrtf(inv1);
    const float bX = p ? W0 : 0.f;

    // ---- P3: distance-decay (skip fully-masked chains: tot == 1 exactly)
    const float dj0 = (float)(i_row - jb0);
    chain_decay(s0a, tl0, dj0, bX + G0, S1, ghs);
    chain_decay(s1a, tl1, dj0 - 64.f, bX + U0 + G1, S1, ghs);
    chain_decay(s2a, tl2, dj0 - 128.f, bX + U0 + U1 + G2, S1, ghs);
    chain_decay(s3a, tl3, dj0 - 192.f, bX + U0 + U1 + U2 + G3, S1, ghs);

    // ---- P4: unmasked softmax numerators, pack p to bf16 (inv2 at epilogue)
    unsigned pk0[8], pk1[8], pk2[8], pk3[8];
    float S2 = 0.f;
    chain_pack(s0a, S2, pk0); chain_pack(s1a, S2, pk1);
    chain_pack(s2a, S2, pk2); chain_pack(s3a, S2, pk3);
    S2 += __shfl_xor(S2, 16, 64);
    S2 += __shfl_xor(S2, 32, 64);
    if (g == 0) red[128 + rbase + (p << 4)] = S2;

    // ---- P5: PV (overlaps the S2 LDS write; no barrier needed before)
    f32x4 acc0 = {0.f, 0.f, 0.f, 0.f}, acc1 = {0.f, 0.f, 0.f, 0.f};
    pv_q(pk0, 0, vfb, acc0, acc1);
    pv_q(pk1, 1, vfb, acc0, acc1);
    pv_q(pk2, 2, vfb, acc0, acc1);
    pv_q(pk3, 3, vfb, acc0, acc1);

    // ---- pair-reduce: p=1 publishes, single barrier, p=0 combines+stores
    if (p) {
      float* dst = accR + (pr << 9) + (lane << 3);
      *(f32x4*)dst = acc0;
      *(f32x4*)(dst + 4) = acc1;
    }
    __syncthreads();  // B2 (covers S2 slots AND accR)
    if (!p) {
      float inv2 = 1.f / (red[128 + rbase] + red[128 + rbase + 16]);
      if (S.zp && i_row == 0) inv2 = 0.f;
      const float* src = accR + (pr << 9) + (lane << 3);
      f32x4 o0 = *(const f32x4*)src;
      f32x4 o1 = *(const f32x4*)(src + 4);
      float iv[4];
#pragma unroll
      for (int r = 0; r < 4; ++r) iv[r] = __shfl(inv2, (g << 2) + r, 64);
      u16* orow = S.O + ((size_t)b * SEQL + i0 + (g << 2)) * DM + h * 32 + c;
#pragma unroll
      for (int r = 0; r < 4; ++r) {
        float v0 = (acc0[r] + o0[r]) * iv[r];
        float v1 = (acc1[r] + o1[r]) * iv[r];
        orow[(size_t)r * DM] = (u16)cvt_pk_bf16(v0, v0);
        orow[(size_t)r * DM + 16] = (u16)cvt_pk_bf16(v1, v1);
      }
    }
  }
}

// ---------------- add + LayerNorm (fp32 in, bf16 out), two sets ----------------
struct LnSet { const float* x; const float* res; int rstride; const float* g; const float* b; u16* out; };
__global__ __launch_bounds__(256, 4) void add_ln(LnSet sa, LnSet sb, int rows0) {
  const int row = (blockIdx.x << 2) + (threadIdx.x >> 6);
  const bool second = row >= rows0;
  const LnSet S = second ? sb : sa;
  const int r = second ? row - rows0 : row;
  const int lane = threadIdx.x & 63;
  float4 xv = *(const float4*)&S.x[(size_t)r * DM + (lane << 2)];
  float4 rv = *(const float4*)&S.res[(size_t)r * S.rstride + (lane << 2)];
  float4 v;
  v.x = xv.x + rv.x; v.y = xv.y + rv.y; v.z = xv.z + rv.z; v.w = xv.w + rv.w;
  float s = wred_sum(v.x + v.y + v.z + v.w);
  const float mean = s * (1.f / 256.f);
  float4 d;
  d.x = v.x - mean; d.y = v.y - mean; d.z = v.z - mean; d.w = v.w - mean;
  float q = wred_sum(d.x * d.x + d.y * d.y + d.z * d.z + d.w * d.w);
  const float rstd = rsqrtf(q * (1.f / 256.f) + 1e-5f);
  float4 gv = *(const float4*)&S.g[lane << 2];
  float4 bv = *(const float4*)&S.b[lane << 2];
  float ox = fmaf(gv.x * d.x, rstd, bv.x), oy = fmaf(gv.y * d.y, rstd, bv.y);
  float oz = fmaf(gv.z * d.z, rstd, bv.z), ow = fmaf(gv.w * d.w, rstd, bv.w);
  uint2 pk2;
  pk2.x = cvt_pk_bf16(ox, oy);
  pk2.y = cvt_pk_bf16(oz, ow);
  *(uint2*)&S.out[(size_t)r * DM + (lane << 2)] = pk2;
}

// ---------------- tiny precompute: q3 (bf16, 0.505-scaled), key3 ----------------
__global__ __launch_bounds__(256) void small_pre(
    const float* know, const float* qw, const float* qb,
    const float* lkw, const float* lkb, u16* q3, float* key3) {
  const int d = threadIdx.x;
  float acc = qb[d];
  for (int kk = 0; kk < 256; ++kk) acc = fmaf(know[kk], qw[kk * 256 + d], acc);
  acc *= SCQ;
  q3[d] = (u16)cvt_pk_bf16(acc, acc);
#pragma unroll
  for (int hh = 0; hh < 8; ++hh) {
    float a = lkb[d];
#pragma unroll
    for (int kk = 0; kk < 32; ++kk)
      a = fmaf(know[hh * 32 + kk], lkw[kk * 256 + d], a);
    key3[hh * 256 + d] = 1.f / (1.f + __expf(-a));
  }
}

// ---------------- final pooling (Hf bf16) ----------------
__global__ __launch_bounds__(256, 4) void final_combine(
    const float* qe, const u16* Hf, const float* key3,
    const float* lvw, const float* lvb, float* out) {
  __shared__ float hl[256];
  __shared__ float red[4][8];
  const int n = blockIdx.x, d = threadIdx.x;
  const int lane = d & 63, wv = d >> 6;
  hl[d] = __uint_as_float(((unsigned)Hf[(size_t)n * DM + d]) << 16);
  const float qd = qe[(size_t)n * DM + d];
  float part[8];
#pragma unroll
  for (int hh = 0; hh < 8; ++hh) part[hh] = wred_sum(key3[hh * 256 + d] * qd);
  if (lane == 0) {
#pragma unroll
    for (int hh = 0; hh < 8; ++hh) red[wv][hh] = part[hh];
  }
  __syncthreads();
  float beta[8];
#pragma unroll
  for (int hh = 0; hh < 8; ++hh)
    beta[hh] = red[0][hh] + red[1][hh] + red[2][hh] + red[3][hh];
  float mb = beta[0];
#pragma unroll
  for (int hh = 1; hh < 8; ++hh) mb = fmaxf(mb, beta[hh]);
  float al[8], se = 0.f;
#pragma unroll
  for (int hh = 0; hh < 8; ++hh) { al[hh] = __expf(beta[hh] - mb); se += al[hh]; }
  const float inva = 1.f / se;
  float acc[8];
#pragma unroll
  for (int hh = 0; hh < 8; ++hh) acc[hh] = 0.f;
#pragma unroll
  for (int kk = 0; kk < 32; ++kk) {
    float w = lvw[kk * 256 + d];
#pragma unroll
    for (int hh = 0; hh < 8; ++hh) acc[hh] = fmaf(hl[hh * 32 + kk], w, acc[hh]);
  }
  const float bd = lvb[d];
  float o = 0.f;
#pragma unroll
  for (int hh = 0; hh < 8; ++hh) {
    float vv = 1.f / (1.f + __expf(-(acc[hh] + bd)));
    o = fmaf(al[hh] * inva, vv, o);
  }
  out[(size_t)n * DM + d] = o;
}

// ---------------- host launch ----------------
extern "C" void kernel_launch(void* const* d_in, const int* in_sizes, int n_in,
                              void* d_out, int out_size, void* d_ws, size_t ws_size,
                              hipStream_t stream) {
  (void)in_sizes; (void)n_in; (void)out_size; (void)ws_size;
  const float* q_emb  = (const float*)d_in[0];
  const float* qa_emb = (const float*)d_in[1];
  const float* b1_qw = (const float*)d_in[2];   const float* b1_qb = (const float*)d_in[3];
  const float* b1_vw = (const float*)d_in[4];   const float* b1_vb = (const float*)d_in[5];
  const float* b1_ow = (const float*)d_in[6];   const float* b1_ob = (const float*)d_in[7];
  const float* b1_gam = (const float*)d_in[8];
  const float* b1_lng = (const float*)d_in[9];  const float* b1_lnb = (const float*)d_in[10];
  const float* b2_qw = (const float*)d_in[11];  const float* b2_qb = (const float*)d_in[12];
  const float* b2_vw = (const float*)d_in[13];  const float* b2_vb = (const float*)d_in[14];
  const float* b2_ow = (const float*)d_in[15];  const float* b2_ob = (const float*)d_in[16];
  const float* b2_gam = (const float*)d_in[17];
  const float* b2_lng = (const float*)d_in[18]; const float* b2_lnb = (const float*)d_in[19];
  const float* b3_qw = (const float*)d_in[20];  const float* b3_qb = (const float*)d_in[21];
  const float* b3_kw = (const float*)d_in[22];  const float* b3_kb = (const float*)d_in[23];
  const float* b3_vw = (const float*)d_in[24];  const float* b3_vb = (const float*)d_in[25];
  const float* b3_ow = (const float*)d_in[26];  const float* b3_ob = (const float*)d_in[27];
  const float* b3_gam = (const float*)d_in[28];
  const float* b3_lng = (const float*)d_in[29]; const float* b3_lnb = (const float*)d_in[30];
  const float* know = (const float*)d_in[31];
  const float* lk_w = (const float*)d_in[32];   const float* lk_b = (const float*)d_in[33];
  const float* lv_w = (const float*)d_in[34];   const float* lv_b = (const float*)d_in[35];

  // workspace layout
  u16* wtb = (u16*)d_ws;                                   // 9*65536*2 = 1179648 B
  u16* q3 = (u16*)((char*)d_ws + 1179648);                 // 512 B
  float* key3 = (float*)((char*)d_ws + 1180160);           // 8192 B
  char* pool = (char*)d_ws + 1188352;
  const size_t SLOT = 2097152;  // elements per buffer (8192*256)
  u16* s0 = (u16*)pool;
  u16* s1 = s0 + SLOT; u16* s2 = s1 + SLOT; u16* s3 = s2 + SLOT;
  u16* s4 = s3 + SLOT; u16* s5 = s4 + SLOT; u16* s6 = s5 + SLOT;
  float* f0 = (float*)(pool + 7 * SLOT * 2);
  float* f1 = f0 + SLOT;

  (void)hipFuncSetAttribute((const void*)attn_fused,
                            hipFuncAttributeMaxDynamicSharedMemorySize, 75776);
  (void)hipFuncSetAttribute((const void*)&gemm_mfma<0, 1>,
                            hipFuncAttributeMaxDynamicSharedMemorySize, 65536);
  (void)hipFuncSetAttribute((const void*)&gemm_mfma<1, 0>,
                            hipFuncAttributeMaxDynamicSharedMemorySize, 65536);
  (void)hipFuncSetAttribute((const void*)&gemm_mfma<1, 1>,
                            hipFuncAttributeMaxDynamicSharedMemorySize, 65536);

  // weight transpose + tiny precompute
  W9 w9{{b1_qw, b1_vw, b1_ow, b2_qw, b2_vw, b2_ow, b3_kw, b3_vw, b3_ow}};
  wt_pre<<<dim3(32, 9), 256, 0, stream>>>(w9, wtb);
  small_pre<<<1, 256, 0, stream>>>(know, b3_qw, b3_qb, lk_w, lk_b, q3, key3);

  // q/v projections for blocks 1&2 (q-buffers pre-scaled by sqrt(SC2))
  GemmBatch g1;
  g1.s[0] = {q_emb,  wtb + 0 * 65536, b1_qb, s0, SCQ};
  g1.s[1] = {q_emb,  wtb + 1 * 65536, b1_vb, s1, 1.f};
  g1.s[2] = {qa_emb, wtb + 3 * 65536, b2_qb, s2, SCQ};
  g1.s[3] = {qa_emb, wtb + 4 * 65536, b2_vb, s3, 1.f};
  gemm_mfma<0, 1><<<dim3(128, 4, 4), 256, 65536, stream>>>(g1);

  // merged attention blocks 1&2
  AttnSet A1{s0, s0, s1, b1_gam, s4, SEQL * DM, DM, 1, 0};
  AttnSet A2{s2, s2, s3, b2_gam, s5, SEQL * DM, DM, 1, 0};
  attn_fused<<<dim3(256, 4), 512, 75776, stream>>>(A1, A2);

  // out-projections
  GemmBatch g2;
  g2.s[0] = {s4, wtb + 2 * 65536, b1_ob, f0, 1.f};
  g2.s[1] = {s5, wtb + 5 * 65536, b2_ob, f1, 1.f};
  g2.s[2] = g2.s[0]; g2.s[3] = g2.s[0];
  gemm_mfma<1, 0><<<dim3(128, 4, 2), 256, 65536, stream>>>(g2);

  // add+LN blocks 1&2 -> HQ (s1), HA (s3)
  LnSet L1{f0, q_emb, DM, b1_lng, b1_lnb, s1};
  LnSet L2{f1, qa_emb, DM, b2_lng, b2_lnb, s3};
  add_ln<<<4096, 256, 0, stream>>>(L1, L2, 8192);

  // block3 k/v projections -> Kb3 (s4, 0.505-scaled), Vb3 (s5)
  GemmBatch g3;
  g3.s[0] = {s1, wtb + 6 * 65536, b3_kb, s4, SCQ};
  g3.s[1] = {s3, wtb + 7 * 65536, b3_vb, s5, 1.f};
  g3.s[2] = g3.s[0]; g3.s[3] = g3.s[0];
  gemm_mfma<1, 1><<<dim3(128, 4, 2), 256, 65536, stream>>>(g3);

  // block3 attention (broadcast q3, strict mask, zero_pad)
  AttnSet A3{q3, s4, s5, b3_gam, s0, 0, 0, 0, 1};
  attn_fused<<<dim3(128, 4), 512, 75776, stream>>>(A3, A3);

  // block3 out-projection + add+LN -> Hf (s6)
  GemmBatch g4;
  g4.s[0] = {s0, wtb + 8 * 65536, b3_ob, f0, 1.f};
  g4.s[1] = g4.s[0]; g4.s[2] = g4.s[0]; g4.s[3] = g4.s[0];
  gemm_mfma<1, 0><<<dim3(128, 4, 1), 256, 65536, stream>>>(g4);
  LnSet L3{f0, know, 0, b3_lng, b3_lnb, s6};
  add_ln<<<2048, 256, 0, stream>>>(L3, L3, 8192);

  // final pooling
  final_combine<<<8192, 256, 0, stream>>>(q_emb, s6, key3, lv_w, lv_b, (float*)d_out);
}

// Round 8
// 209.014 us; speedup vs baseline: 4.2706x; 1.0380x over previous
//
#include <hip/hip_runtime.h>
#include <stdint.h>

constexpr int SEQL = 512;
constexpr int DM = 256;
constexpr float SCQ = 0.50500066f;  // sqrt(1/sqrt(32) * log2(e))

typedef __attribute__((ext_vector_type(4))) float f32x4;
typedef __attribute__((ext_vector_type(8))) short short8;
typedef unsigned short u16;

// ---------------- helpers ----------------
__device__ __forceinline__ unsigned cvt_pk_bf16(float lo, float hi) {
  unsigned r;
  asm("v_cvt_pk_bf16_f32 %0, %1, %2" : "=v"(r) : "v"(lo), "v"(hi));
  return r;
}
__device__ __forceinline__ void gload_lds16(const void* g, void* l) {
  __builtin_amdgcn_global_load_lds(
      (const __attribute__((address_space(1))) void*)g,
      (__attribute__((address_space(3))) void*)l, 16, 0, 0);
}
__device__ __forceinline__ float wred_sum(float v) {
#pragma unroll
  for (int d = 32; d >= 1; d >>= 1) v += __shfl_xor(v, d, 64);
  return v;
}

// ---------------- weight pre-transpose: Wt[n][k] bf16 ----------------
struct W9 { const float* w[9]; };
__global__ __launch_bounds__(256) void wt_pre(W9 wlist, u16* out) {
  const float* W = wlist.w[blockIdx.y];
  const int n = threadIdx.x;
  const int k8 = blockIdx.x << 3;
  float v[8];
#pragma unroll
  for (int e = 0; e < 8; ++e) v[e] = W[(size_t)(k8 + e) * 256 + n];
  unsigned u4[4];
#pragma unroll
  for (int e2 = 0; e2 < 4; ++e2) u4[e2] = cvt_pk_bf16(v[2 * e2], v[2 * e2 + 1]);
  u16* dst = out + (size_t)blockIdx.y * 65536 + (size_t)n * 256 + k8;
  *(uint4*)dst = make_uint4(u4[0], u4[1], u4[2], u4[3]);
}

// ---------------- bf16 MFMA GEMM: C[8192,256] = A[8192,256]@W + bias, xscale ----------------
struct GemmSet { const void* A; const u16* Wt; const float* bias; void* C; float scale; };
struct GemmBatch { GemmSet s[4]; };

template <int ABF16, int OBF16>
__global__ __launch_bounds__(256, 2) void gemm_mfma(GemmBatch batch) {
  extern __shared__ char lds[];
  char* Al = lds;          // 32KB: A tile 64x256 bf16, XOR-swizzled
  char* Wl = lds + 32768;  // 32KB: Wt tile 64x256 bf16, XOR-swizzled
  const GemmSet S = batch.s[blockIdx.z];
  const int tid = threadIdx.x, lane = tid & 63, wave = tid >> 6;
  const int m0 = blockIdx.x << 6, n0 = blockIdx.y << 6;

#pragma unroll
  for (int it = 0; it < 8; ++it) {
    int chunk = (it << 8) + tid;
    int row = chunk >> 5, cc = chunk & 31;
    gload_lds16(S.Wt + (size_t)(n0 + row) * 256 + ((cc ^ (row & 7)) << 3),
                Wl + (it << 12) + (wave << 10));
  }
  if constexpr (ABF16) {
#pragma unroll
    for (int it = 0; it < 8; ++it) {
      int chunk = (it << 8) + tid;
      int row = chunk >> 5, cc = chunk & 31;
      gload_lds16((const u16*)S.A + (size_t)(m0 + row) * 256 + ((cc ^ (row & 7)) << 3),
                  Al + (it << 12) + (wave << 10));
    }
  } else {
#pragma unroll
    for (int it = 0; it < 16; ++it) {
      int idx = (it << 8) + tid;
      int row = idx >> 6, k4 = (idx & 63) << 2;
      float4 v = *(const float4*)((const float*)S.A + (size_t)(m0 + row) * 256 + k4);
      uint2 pk2;
      pk2.x = cvt_pk_bf16(v.x, v.y);
      pk2.y = cvt_pk_bf16(v.z, v.w);
      *(uint2*)(Al + (row << 9) + ((k4 << 1) ^ ((row & 7) << 4))) = pk2;
    }
  }
  __syncthreads();

  const int g = lane >> 4, cc = lane & 15;
  const int sw = cc & 7;
  f32x4 acc[4];
#pragma unroll
  for (int j = 0; j < 4; ++j) acc[j] = (f32x4){0.f, 0.f, 0.f, 0.f};
  const char* arow = Al + (size_t)((wave << 4) + cc) * 512;
  const char* wrow = Wl + (size_t)cc * 512;
#pragma unroll
  for (int kk = 0; kk < 8; ++kk) {
    const int so = (((kk << 2) + g) ^ sw) << 4;
    short8 ka = *(const short8*)(arow + so);
#pragma unroll
    for (int j = 0; j < 4; ++j) {
      short8 kb = *(const short8*)(wrow + (j << 13) + so);
      acc[j] = __builtin_amdgcn_mfma_f32_16x16x32_bf16(ka, kb, acc[j], 0, 0, 0);
    }
  }
#pragma unroll
  for (int j = 0; j < 4; ++j) {
    float bj = S.bias[n0 + (j << 4) + cc];
#pragma unroll
    for (int r = 0; r < 4; ++r) {
      float v = (acc[j][r] + bj) * S.scale;
      size_t off = (size_t)(m0 + (wave << 4) + (g << 2) + r) * 256 + n0 + (j << 4) + cc;
      if constexpr (OBF16)
        ((u16*)S.C)[off] = (u16)cvt_pk_bf16(v, v);
      else
        ((float*)S.C)[off] = v;
    }
  }
}

// ---------------- attention chain helpers (log2 domain, NO max-subtraction) ----------------
// m1 = m2 = 0 is numerically safe: scores pre-scaled by log2e/sqrt(32),
// exp2 args stay in [-10,10] with huge fp32 margin.
__device__ __forceinline__ float chain_sum(const float (&sq)[16], int tlq) {
  if (!__any(tlq >= 0)) return 0.f;
  float t = 0.f;
  if (__all(tlq >= 15)) {
#pragma unroll
    for (int T = 0; T < 16; ++T) t += __builtin_amdgcn_exp2f(sq[T]);
  } else {
#pragma unroll
    for (int T = 0; T < 16; ++T)
      t += (T <= tlq) ? __builtin_amdgcn_exp2f(sq[T]) : 0.f;
  }
  return t;
}
__device__ __forceinline__ void chain_decay(float (&sq)[16], int tlq, float djq, float seed,
                                            float S1, float ghs) {
  if (!__any(tlq >= 0)) return;  // fully masked: tot == 1 exactly
  float r = seed;
  if (__all(tlq >= 15)) {
#pragma unroll
    for (int T = 0; T < 16; ++T) {
      r += __builtin_amdgcn_exp2f(sq[T]);
      float u = fmaxf((S1 - r) * (djq - (float)T), 0.f);
      float tot = fmaxf(__builtin_amdgcn_exp2f(ghs * __builtin_amdgcn_sqrtf(u)), 1e-5f);
      sq[T] *= tot;  // ghs <= 0 so tot <= 1: upper clip never active
    }
  } else {
#pragma unroll
    for (int T = 0; T < 16; ++T) {
      float e = (T <= tlq) ? __builtin_amdgcn_exp2f(sq[T]) : 0.f;
      r += e;
      float u = fmaxf((S1 - r) * (djq - (float)T), 0.f);
      float tot = fmaxf(__builtin_amdgcn_exp2f(ghs * __builtin_amdgcn_sqrtf(u)), 1e-5f);
      sq[T] *= tot;
    }
  }
}
// r4-verified: pack ALL chains first, then PV (r5's interleaved variant failed).
__device__ __forceinline__ void chain_pack(const float (&sq)[16], float& S2,
                                           unsigned (&pkq)[8]) {
#pragma unroll
  for (int k = 0; k < 8; ++k) {
    float pa = __builtin_amdgcn_exp2f(sq[2 * k]);
    float pb = __builtin_amdgcn_exp2f(sq[2 * k + 1]);
    S2 += pa + pb;
    pkq[k] = cvt_pk_bf16(pa, pb);
  }
}
__device__ __forceinline__ void pv_q(const unsigned (&pkq)[8], int qidx, const char* vfb,
                                     f32x4& acc0, f32x4& acc1) {
#pragma unroll
  for (int hf = 0; hf < 2; ++hf) {
    union { unsigned u[4]; short8 s8; } ua;
    ua.u[0] = pkq[hf * 4 + 0]; ua.u[1] = pkq[hf * 4 + 1];
    ua.u[2] = pkq[hf * 4 + 2]; ua.u[3] = pkq[hf * 4 + 3];
    const int st = qidx * 2 + hf;
    short8 vb0 = *(const short8*)(vfb + (st << 11));
    short8 vb1 = *(const short8*)(vfb + (st << 11) + 1024);
    acc0 = __builtin_amdgcn_mfma_f32_16x16x32_bf16(ua.s8, vb0, acc0, 0, 0, 0);
    acc1 = __builtin_amdgcn_mfma_f32_16x16x32_bf16(ua.s8, vb1, acc1, 0, 0, 0);
  }
}

// ---------------- fused attention (bf16 in, bf16 out) ----------------
// BALANCED-J: j = 128q + 64p + 16g + T — wave pair interleaves 64-j blocks so
// causal-mask work is even within each pair (r7 was 256p+64q: one wave did up
// to 2x the exp work and the barriers convoyed on the max).
// Cross-wave prefix needs per-chain totals now: E(q,p) = sum_{q'<q}(U+B) + p*B_q.
// 2 barriers/iter (B1 after chain totals, B2 covers S2 slots + accR).
struct AttnSet {
  const u16* Q; const u16* K; const u16* V;
  const float* gam; u16* O;
  int qsb, qss, peek, zp;
};

// (512,2): live state ~90-100 VGPR; min-waves=4 forces the 64-VGPR bucket and
// spills ~420MB/dispatch (r4 post-mortem). LDS-limited to 2 blocks/CU anyway.
__global__ __launch_bounds__(512, 2) void attn_fused(AttnSet a0, AttnSet a1) {
  extern __shared__ char smem[];
  char* KlB = smem;                      // 32KB K bf16, permuted rows
  char* VfB = smem + 32768;              // 32KB V B-fragments
  float* accR = (float*)(smem + 65536);  // 8KB pair-reduce
  float* red = (float*)(smem + 73728);   // 2.5KB: [4 chains][4 pr][2 p][16 c] + S2
  const int tid = threadIdx.x;
  const int lane = tid & 63, wave = tid >> 6;
  const int p = wave & 1, pr = wave >> 1;
  const AttnSet S = (blockIdx.x >> 7) ? a1 : a0;
  const int bh = blockIdx.x & 127;
  const int b = bh >> 3, h = bh & 7;
  const int y = blockIdx.y;
  const int g = lane >> 4, c = lane & 15;

  // ---- stage K via global_load_lds; source permuted for j = 128q+64p+16g+T
  const u16* Kb = S.K + ((size_t)b * SEQL) * DM + h * 32;
#pragma unroll
  for (int it = 0; it < 4; ++it) {
    int chunk = (it << 9) + tid;
    int row = chunk >> 2, c16 = chunk & 3;
    int j = ((row & 3) << 7) + ((row >> 8) << 6) + (((row >> 2) & 3) << 4) + ((row >> 4) & 15);
    gload_lds16(Kb + (size_t)j * DM + (c16 << 3), KlB + (it << 13) + (wave << 10));
  }
  // ---- stage V scattered into PV B-fragment order (new field extraction)
  const u16* Vb = S.V + ((size_t)b * SEQL) * DM + h * 32;
#pragma unroll
  for (int it = 0; it < 4; ++it) {
    int idx = (it << 9) + tid;
    int j = idx >> 2, dc = idx & 3, d0 = dc << 3;
    short8 v = *(const short8*)(Vb + (size_t)j * DM + d0);
    int q_ = j >> 7, p_ = (j >> 6) & 1, g_ = (j >> 4) & 3, tt = j & 15;
    int st_ = (q_ << 1) + (tt >> 3), e_ = tt & 7;
    char* base = VfB + (((p_ << 4) + (st_ << 1) + (d0 >> 4)) << 10) +
                 (((g_ << 4) + (d0 & 15)) << 4) + (e_ << 1);
    const unsigned* vu = (const unsigned*)&v;
#pragma unroll
    for (int e = 0; e < 4; ++e) {
      *(u16*)(base + (e << 5)) = (u16)(vu[e] & 0xffffu);
      *(u16*)(base + (e << 5) + 16) = (u16)(vu[e] >> 16);
    }
  }
  __syncthreads();

  const float gh2 = -log1pf(__expf(S.gam[h])) * 1.4426950408889634f;
  const char* kfb = KlB + (p << 14) + c * 64 + (g << 4);
  const char* vfb = VfB + (p << 14) + (lane << 4);
  const int rbase = (pr << 5) + c;
  const int jb0 = (p << 6) + (g << 4);

  for (int it = 0; it < 2; ++it) {
    const int sl = it ? (7 - y) : y;
    const int i0 = (sl << 6) + (pr << 4);
    const int i_row = i0 + c;
    short8 qf = *(const short8*)(S.Q + (size_t)b * S.qsb + (size_t)i_row * S.qss + h * 32 + (g << 3));

    // ---- QK^T (swapped): chain q holds j = 128q + 64p + 16g + T
    float s0a[16], s1a[16], s2a[16], s3a[16];
#pragma unroll
    for (int T = 0; T < 16; ++T) {
      short8 ka = *(const short8*)(kfb + (T << 10));
      f32x4 d = __builtin_amdgcn_mfma_f32_16x16x32_bf16(
          ka, qf, (f32x4){0.f, 0.f, 0.f, 0.f}, 0, 0, 0);
      s0a[T] = d.x; s1a[T] = d.y; s2a[T] = d.z; s3a[T] = d.w;
    }
    const int ilim = i_row - 1 + S.peek;
    const int tl0 = ilim - jb0, tl1 = tl0 - 128, tl2 = tl0 - 256, tl3 = tl0 - 384;

    // ---- P2: masked-exp chain totals + within-chain g-scan
    float T0 = chain_sum(s0a, tl0), T1 = chain_sum(s1a, tl1);
    float T2 = chain_sum(s2a, tl2), T3 = chain_sum(s3a, tl3);
    float i0v = T0, i1v = T1, i2v = T2, i3v = T3, tU;
    tU = __shfl_up(i0v, 16, 64); i0v += (g >= 1) ? tU : 0.f;
    tU = __shfl_up(i0v, 32, 64); i0v += (g >= 2) ? tU : 0.f;
    tU = __shfl_up(i1v, 16, 64); i1v += (g >= 1) ? tU : 0.f;
    tU = __shfl_up(i1v, 32, 64); i1v += (g >= 2) ? tU : 0.f;
    tU = __shfl_up(i2v, 16, 64); i2v += (g >= 1) ? tU : 0.f;
    tU = __shfl_up(i2v, 32, 64); i2v += (g >= 2) ? tU : 0.f;
    tU = __shfl_up(i3v, 16, 64); i3v += (g >= 1) ? tU : 0.f;
    tU = __shfl_up(i3v, 32, 64); i3v += (g >= 2) ? tU : 0.f;
    float U0 = __shfl(i0v, c + 48, 64), U1 = __shfl(i1v, c + 48, 64);
    float U2 = __shfl(i2v, c + 48, 64), U3 = __shfl(i3v, c + 48, 64);
    float G0 = i0v - T0, G1 = i1v - T1, G2 = i2v - T2, G3 = i3v - T3;
    if (g == 0) {
      float* rT = red + rbase + (p << 4);
      rT[0] = U0; rT[128] = U1; rT[256] = U2; rT[384] = U3;
    }
    __syncthreads();  // B1
    const float* rO = red + rbase + ((1 - p) << 4);  // other wave's chain totals
    const float O0 = rO[0], O1 = rO[128], O2 = rO[256], O3 = rO[384];
    const float c1 = U0 + O0, c2 = c1 + U1 + O1, c3 = c2 + U2 + O2;
    const float S1 = c3 + U3 + O3;
    const float inv1 = (S1 > 0.f) ? (1.f / S1) : 0.f;
    const float ghs = gh2 * __builtin_amdgcn_sqrtf(inv1);
    // exclusive prefix in j-order (blocks ordered (q,p)): E_q = pre + p*O_q
    const float E0 = p ? O0 : 0.f;
    const float E1 = c1 + (p ? O1 : 0.f);
    const float E2 = c2 + (p ? O2 : 0.f);
    const float E3 = c3 + (p ? O3 : 0.f);

    // ---- P3: distance-decay (chain q window base = 128q + jb0)
    const float dj0 = (float)(i_row - jb0);
    chain_decay(s0a, tl0, dj0, E0 + G0, S1, ghs);
    chain_decay(s1a, tl1, dj0 - 128.f, E1 + G1, S1, ghs);
    chain_decay(s2a, tl2, dj0 - 256.f, E2 + G2, S1, ghs);
    chain_decay(s3a, tl3, dj0 - 384.f, E3 + G3, S1, ghs);

    // ---- P4: unmasked softmax numerators, pack p to bf16 (inv2 at epilogue)
    unsigned pk0[8], pk1[8], pk2[8], pk3[8];
    float S2 = 0.f;
    chain_pack(s0a, S2, pk0); chain_pack(s1a, S2, pk1);
    chain_pack(s2a, S2, pk2); chain_pack(s3a, S2, pk3);
    S2 += __shfl_xor(S2, 16, 64);
    S2 += __shfl_xor(S2, 32, 64);
    if (g == 0) red[512 + rbase + (p << 4)] = S2;

    // ---- P5: PV (overlaps the S2 LDS write)
    f32x4 acc0 = {0.f, 0.f, 0.f, 0.f}, acc1 = {0.f, 0.f, 0.f, 0.f};
    pv_q(pk0, 0, vfb, acc0, acc1);
    pv_q(pk1, 1, vfb, acc0, acc1);
    pv_q(pk2, 2, vfb, acc0, acc1);
    pv_q(pk3, 3, vfb, acc0, acc1);

    // ---- pair-reduce: p=1 publishes, single barrier, p=0 combines+stores
    if (p) {
      float* dst = accR + (pr << 9) + (lane << 3);
      *(f32x4*)dst = acc0;
      *(f32x4*)(dst + 4) = acc1;
    }
    __syncthreads();  // B2 (covers S2 slots AND accR)
    if (!p) {
      float inv2 = 1.f / (red[512 + rbase] + red[512 + rbase + 16]);
      if (S.zp && i_row == 0) inv2 = 0.f;
      const float* src = accR + (pr << 9) + (lane << 3);
      f32x4 o0 = *(const f32x4*)src;
      f32x4 o1 = *(const f32x4*)(src + 4);
      float iv[4];
#pragma unroll
      for (int r = 0; r < 4; ++r) iv[r] = __shfl(inv2, (g << 2) + r, 64);
      u16* orow = S.O + ((size_t)b * SEQL + i0 + (g << 2)) * DM + h * 32 + c;
#pragma unroll
      for (int r = 0; r < 4; ++r) {
        float v0 = (acc0[r] + o0[r]) * iv[r];
        float v1 = (acc1[r] + o1[r]) * iv[r];
        orow[(size_t)r * DM] = (u16)cvt_pk_bf16(v0, v0);
        orow[(size_t)r * DM + 16] = (u16)cvt_pk_bf16(v1, v1);
      }
    }
  }
}

// ---------------- add + LayerNorm (fp32 in, bf16 out), two sets ----------------
struct LnSet { const float* x; const float* res; int rstride; const float* g; const float* b; u16* out; };
__global__ __launch_bounds__(256, 4) void add_ln(LnSet sa, LnSet sb, int rows0) {
  const int row = (blockIdx.x << 2) + (threadIdx.x >> 6);
  const bool second = row >= rows0;
  const LnSet S = second ? sb : sa;
  const int r = second ? row - rows0 : row;
  const int lane = threadIdx.x & 63;
  float4 xv = *(const float4*)&S.x[(size_t)r * DM + (lane << 2)];
  float4 rv = *(const float4*)&S.res[(size_t)r * S.rstride + (lane << 2)];
  float4 v;
  v.x = xv.x + rv.x; v.y = xv.y + rv.y; v.z = xv.z + rv.z; v.w = xv.w + rv.w;
  float s = wred_sum(v.x + v.y + v.z + v.w);
  const float mean = s * (1.f / 256.f);
  float4 d;
  d.x = v.x - mean; d.y = v.y - mean; d.z = v.z - mean; d.w = v.w - mean;
  float q = wred_sum(d.x * d.x + d.y * d.y + d.z * d.z + d.w * d.w);
  const float rstd = rsqrtf(q * (1.f / 256.f) + 1e-5f);
  float4 gv = *(const float4*)&S.g[lane << 2];
  float4 bv = *(const float4*)&S.b[lane << 2];
  float ox = fmaf(gv.x * d.x, rstd, bv.x), oy = fmaf(gv.y * d.y, rstd, bv.y);
  float oz = fmaf(gv.z * d.z, rstd, bv.z), ow = fmaf(gv.w * d.w, rstd, bv.w);
  uint2 pk2;
  pk2.x = cvt_pk_bf16(ox, oy);
  pk2.y = cvt_pk_bf16(oz, ow);
  *(uint2*)&S.out[(size_t)r * DM + (lane << 2)] = pk2;
}

// ---------------- tiny precompute: q3 (bf16, 0.505-scaled), key3 ----------------
__global__ __launch_bounds__(256) void small_pre(
    const float* know, const float* qw, const float* qb,
    const float* lkw, const float* lkb, u16* q3, float* key3) {
  const int d = threadIdx.x;
  float acc = qb[d];
  for (int kk = 0; kk < 256; ++kk) acc = fmaf(know[kk], qw[kk * 256 + d], acc);
  acc *= SCQ;
  q3[d] = (u16)cvt_pk_bf16(acc, acc);
#pragma unroll
  for (int hh = 0; hh < 8; ++hh) {
    float a = lkb[d];
#pragma unroll
    for (int kk = 0; kk < 32; ++kk)
      a = fmaf(know[hh * 32 + kk], lkw[kk * 256 + d], a);
    key3[hh * 256 + d] = 1.f / (1.f + __expf(-a));
  }
}

// ---------------- final pooling (Hf bf16) ----------------
__global__ __launch_bounds__(256, 4) void final_combine(
    const float* qe, const u16* Hf, const float* key3,
    const float* lvw, const float* lvb, float* out) {
  __shared__ float hl[256];
  __shared__ float red[4][8];
  const int n = blockIdx.x, d = threadIdx.x;
  const int lane = d & 63, wv = d >> 6;
  hl[d] = __uint_as_float(((unsigned)Hf[(size_t)n * DM + d]) << 16);
  const float qd = qe[(size_t)n * DM + d];
  float part[8];
#pragma unroll
  for (int hh = 0; hh < 8; ++hh) part[hh] = wred_sum(key3[hh * 256 + d] * qd);
  if (lane == 0) {
#pragma unroll
    for (int hh = 0; hh < 8; ++hh) red[wv][hh] = part[hh];
  }
  __syncthreads();
  float beta[8];
#pragma unroll
  for (int hh = 0; hh < 8; ++hh)
    beta[hh] = red[0][hh] + red[1][hh] + red[2][hh] + red[3][hh];
  float mb = beta[0];
#pragma unroll
  for (int hh = 1; hh < 8; ++hh) mb = fmaxf(mb, beta[hh]);
  float al[8], se = 0.f;
#pragma unroll
  for (int hh = 0; hh < 8; ++hh) { al[hh] = __expf(beta[hh] - mb); se += al[hh]; }
  const float inva = 1.f / se;
  float acc[8];
#pragma unroll
  for (int hh = 0; hh < 8; ++hh) acc[hh] = 0.f;
#pragma unroll
  for (int kk = 0; kk < 32; ++kk) {
    float w = lvw[kk * 256 + d];
#pragma unroll
    for (int hh = 0; hh < 8; ++hh) acc[hh] = fmaf(hl[hh * 32 + kk], w, acc[hh]);
  }
  const float bd = lvb[d];
  float o = 0.f;
#pragma unroll
  for (int hh = 0; hh < 8; ++hh) {
    float vv = 1.f / (1.f + __expf(-(acc[hh] + bd)));
    o = fmaf(al[hh] * inva, vv, o);
  }
  out[(size_t)n * DM + d] = o;
}

// ---------------- host launch ----------------
extern "C" void kernel_launch(void* const* d_in, const int* in_sizes, int n_in,
                              void* d_out, int out_size, void* d_ws, size_t ws_size,
                              hipStream_t stream) {
  (void)in_sizes; (void)n_in; (void)out_size; (void)ws_size;
  const float* q_emb  = (const float*)d_in[0];
  const float* qa_emb = (const float*)d_in[1];
  const float* b1_qw = (const float*)d_in[2];   const float* b1_qb = (const float*)d_in[3];
  const float* b1_vw = (const float*)d_in[4];   const float* b1_vb = (const float*)d_in[5];
  const float* b1_ow = (const float*)d_in[6];   const float* b1_ob = (const float*)d_in[7];
  const float* b1_gam = (const float*)d_in[8];
  const float* b1_lng = (const float*)d_in[9];  const float* b1_lnb = (const float*)d_in[10];
  const float* b2_qw = (const float*)d_in[11];  const float* b2_qb = (const float*)d_in[12];
  const float* b2_vw = (const float*)d_in[13];  const float* b2_vb = (const float*)d_in[14];
  const float* b2_ow = (const float*)d_in[15];  const float* b2_ob = (const float*)d_in[16];
  const float* b2_gam = (const float*)d_in[17];
  const float* b2_lng = (const float*)d_in[18]; const float* b2_lnb = (const float*)d_in[19];
  const float* b3_qw = (const float*)d_in[20];  const float* b3_qb = (const float*)d_in[21];
  const float* b3_kw = (const float*)d_in[22];  const float* b3_kb = (const float*)d_in[23];
  const float* b3_vw = (const float*)d_in[24];  const float* b3_vb = (const float*)d_in[25];
  const float* b3_ow = (const float*)d_in[26];  const float* b3_ob = (const float*)d_in[27];
  const float* b3_gam = (const float*)d_in[28];
  const float* b3_lng = (const float*)d_in[29]; const float* b3_lnb = (const float*)d_in[30];
  const float* know = (const float*)d_in[31];
  const float* lk_w = (const float*)d_in[32];   const float* lk_b = (const float*)d_in[33];
  const float* lv_w = (const float*)d_in[34];   const float* lv_b = (const float*)d_in[35];

  // workspace layout
  u16* wtb = (u16*)d_ws;                                   // 9*65536*2 = 1179648 B
  u16* q3 = (u16*)((char*)d_ws + 1179648);                 // 512 B
  float* key3 = (float*)((char*)d_ws + 1180160);           // 8192 B
  char* pool = (char*)d_ws + 1188352;
  const size_t SLOT = 2097152;  // elements per buffer (8192*256)
  u16* s0 = (u16*)pool;
  u16* s1 = s0 + SLOT; u16* s2 = s1 + SLOT; u16* s3 = s2 + SLOT;
  u16* s4 = s3 + SLOT; u16* s5 = s4 + SLOT; u16* s6 = s5 + SLOT;
  float* f0 = (float*)(pool + 7 * SLOT * 2);
  float* f1 = f0 + SLOT;

  const int SMB = 76288;  // 32K K + 32K Vfrag + 8K accR + 2.5K red
  (void)hipFuncSetAttribute((const void*)attn_fused,
                            hipFuncAttributeMaxDynamicSharedMemorySize, SMB);
  (void)hipFuncSetAttribute((const void*)&gemm_mfma<0, 1>,
                            hipFuncAttributeMaxDynamicSharedMemorySize, 65536);
  (void)hipFuncSetAttribute((const void*)&gemm_mfma<1, 0>,
                            hipFuncAttributeMaxDynamicSharedMemorySize, 65536);
  (void)hipFuncSetAttribute((const void*)&gemm_mfma<1, 1>,
                            hipFuncAttributeMaxDynamicSharedMemorySize, 65536);

  // weight transpose + tiny precompute
  W9 w9{{b1_qw, b1_vw, b1_ow, b2_qw, b2_vw, b2_ow, b3_kw, b3_vw, b3_ow}};
  wt_pre<<<dim3(32, 9), 256, 0, stream>>>(w9, wtb);
  small_pre<<<1, 256, 0, stream>>>(know, b3_qw, b3_qb, lk_w, lk_b, q3, key3);

  // q/v projections for blocks 1&2 (q-buffers pre-scaled by sqrt(SC2))
  GemmBatch g1;
  g1.s[0] = {q_emb,  wtb + 0 * 65536, b1_qb, s0, SCQ};
  g1.s[1] = {q_emb,  wtb + 1 * 65536, b1_vb, s1, 1.f};
  g1.s[2] = {qa_emb, wtb + 3 * 65536, b2_qb, s2, SCQ};
  g1.s[3] = {qa_emb, wtb + 4 * 65536, b2_vb, s3, 1.f};
  gemm_mfma<0, 1><<<dim3(128, 4, 4), 256, 65536, stream>>>(g1);

  // merged attention blocks 1&2
  AttnSet A1{s0, s0, s1, b1_gam, s4, SEQL * DM, DM, 1, 0};
  AttnSet A2{s2, s2, s3, b2_gam, s5, SEQL * DM, DM, 1, 0};
  attn_fused<<<dim3(256, 4), 512, SMB, stream>>>(A1, A2);

  // out-projections
  GemmBatch g2;
  g2.s[0] = {s4, wtb + 2 * 65536, b1_ob, f0, 1.f};
  g2.s[1] = {s5, wtb + 5 * 65536, b2_ob, f1, 1.f};
  g2.s[2] = g2.s[0]; g2.s[3] = g2.s[0];
  gemm_mfma<1, 0><<<dim3(128, 4, 2), 256, 65536, stream>>>(g2);

  // add+LN blocks 1&2 -> HQ (s1), HA (s3)
  LnSet L1{f0, q_emb, DM, b1_lng, b1_lnb, s1};
  LnSet L2{f1, qa_emb, DM, b2_lng, b2_lnb, s3};
  add_ln<<<4096, 256, 0, stream>>>(L1, L2, 8192);

  // block3 k/v projections -> Kb3 (s4, 0.505-scaled), Vb3 (s5)
  GemmBatch g3;
  g3.s[0] = {s1, wtb + 6 * 65536, b3_kb, s4, SCQ};
  g3.s[1] = {s3, wtb + 7 * 65536, b3_vb, s5, 1.f};
  g3.s[2] = g3.s[0]; g3.s[3] = g3.s[0];
  gemm_mfma<1, 1><<<dim3(128, 4, 2), 256, 65536, stream>>>(g3);

  // block3 attention (broadcast q3, strict mask, zero_pad)
  AttnSet A3{q3, s4, s5, b3_gam, s0, 0, 0, 0, 1};
  attn_fused<<<dim3(128, 4), 512, SMB, stream>>>(A3, A3);

  // block3 out-projection + add+LN -> Hf (s6)
  GemmBatch g4;
  g4.s[0] = {s0, wtb + 8 * 65536, b3_ob, f0, 1.f};
  g4.s[1] = g4.s[0]; g4.s[2] = g4.s[0]; g4.s[3] = g4.s[0];
  gemm_mfma<1, 0><<<dim3(128, 4, 1), 256, 65536, stream>>>(g4);
  LnSet L3{f0, know, 0, b3_lng, b3_lnb, s6};
  add_ln<<<2048, 256, 0, stream>>>(L3, L3, 8192);

  // final pooling
  final_combine<<<8192, 256, 0, stream>>>(q_emb, s6, key3, lv_w, lv_b, (float*)d_out);
}